// Round 9
// baseline (316.106 us; speedup 1.0000x reference)
//
#include <hip/hip_runtime.h>

#define NB 4
#define SEQ 4096
#define DIM 1024
#define DFF 4096
#define KSEL 2048
#define NTOK (NB * SEQ)   // 16384
#define MR (NB * KSEL)    // 8192

typedef float f32x4_t __attribute__((ext_vector_type(4)));
typedef __bf16 bf16x8_t __attribute__((ext_vector_type(8)));

__device__ __forceinline__ unsigned short f2bf(float f) {
  union { float f; unsigned u; } v; v.f = f;
  unsigned r = v.u + 0x7fffu + ((v.u >> 16) & 1u);  // RNE
  return (unsigned short)(r >> 16);
}

#define GLD16(g, l) __builtin_amdgcn_global_load_lds( \
    (const __attribute__((address_space(1))) void*)(g), \
    (__attribute__((address_space(3))) void*)(l), 16, 0, 0)

// ---- router GEMV (one wave per row) ----
__global__ void router_kernel(const float* __restrict__ x, const float* __restrict__ Wr,
                              const float* __restrict__ br,
                              float* __restrict__ logits, float* __restrict__ scores) {
  int lane = threadIdx.x & 63;
  int wid  = threadIdx.x >> 6;
  int row  = blockIdx.x * 4 + wid;            // 0..16383
  const float4* xr = (const float4*)(x + (size_t)row * DIM);
  const float4* w4 = (const float4*)Wr;
  float sum = 0.f;
#pragma unroll
  for (int i = 0; i < 4; ++i) {
    float4 a = xr[lane + i * 64];
    float4 w = w4[lane + i * 64];
    sum += a.x * w.x + a.y * w.y + a.z * w.z + a.w * w.w;
  }
#pragma unroll
  for (int off = 32; off > 0; off >>= 1) sum += __shfl_down(sum, off);
  if (lane == 0) {
    float l = sum + br[0];
    logits[row] = l;
    scores[row] = 1.f / (1.f + expf(-l));
  }
}

// ---- exact top-k via rank counting (matches jax.lax.top_k tie-break) ----
__global__ void rank_kernel(const float* __restrict__ scores, int* __restrict__ sel) {
  __shared__ float s_sc[SEQ];
  int batch = blockIdx.x >> 8;        // 256 blocks per batch
  int chunk = blockIdx.x & 255;
  int t = threadIdx.x;                // 256
  const float4* sb4 = (const float4*)(scores + batch * SEQ);
  float4* ls4 = (float4*)s_sc;
#pragma unroll
  for (int i = 0; i < 4; ++i) ls4[t + i * 256] = sb4[t + i * 256];
  __syncthreads();
  int tok = chunk * 16 + (t >> 4);    // token this thread contributes to
  int sg  = t & 15;                   // score segment 0..15 (256 scores each)
  float s = s_sc[tok];
  const float4* seg = ls4 + sg * 64;
  int jbase = sg * 256;
  int rank = 0;
#pragma unroll 4
  for (int j4 = 0; j4 < 64; ++j4) {
    float4 v = seg[j4];
    int j = jbase + j4 * 4;
    rank += (v.x > s || (v.x == s && j     < tok)) ? 1 : 0;
    rank += (v.y > s || (v.y == s && j + 1 < tok)) ? 1 : 0;
    rank += (v.z > s || (v.z == s && j + 2 < tok)) ? 1 : 0;
    rank += (v.w > s || (v.w == s && j + 3 < tok)) ? 1 : 0;
  }
#pragma unroll
  for (int off = 8; off > 0; off >>= 1) rank += __shfl_down(rank, off, 16);
  if (sg == 0) sel[batch * SEQ + tok] = (rank < KSEL) ? 1 : 0;
}

// ---- per-batch: softmax over selected scores + prefix-sum compaction ----
__global__ void pack_kernel(const float* __restrict__ scores, const int* __restrict__ sel,
                            int* __restrict__ rows, float* __restrict__ rwv,
                            int* __restrict__ slot) {
  __shared__ float red[16];
  __shared__ int scn[1024];
  int batch = blockIdx.x;
  int t = threadIdx.x;
  const float* sb = scores + batch * SEQ;
  const int* fb = sel + batch * SEQ;
  float sc[4]; int fl[4];
#pragma unroll
  for (int i = 0; i < 4; ++i) { sc[i] = sb[t * 4 + i]; fl[i] = fb[t * 4 + i]; }
  float m = fmaxf(fmaxf(sc[0], sc[1]), fmaxf(sc[2], sc[3]));
#pragma unroll
  for (int off = 32; off > 0; off >>= 1) m = fmaxf(m, __shfl_down(m, off));
  if ((t & 63) == 0) red[t >> 6] = m;
  __syncthreads();
  if (t == 0) { float v = red[0]; for (int i = 1; i < 16; ++i) v = fmaxf(v, red[i]); red[0] = v; }
  __syncthreads();
  m = red[0];
  __syncthreads();
  float ex[4]; float esum = 0.f;
#pragma unroll
  for (int i = 0; i < 4; ++i) { ex[i] = expf(sc[i] - m); if (fl[i]) esum += ex[i]; }
#pragma unroll
  for (int off = 32; off > 0; off >>= 1) esum += __shfl_down(esum, off);
  if ((t & 63) == 0) red[t >> 6] = esum;
  __syncthreads();
  if (t == 0) { float v = 0.f; for (int i = 0; i < 16; ++i) v += red[i]; red[0] = v; }
  __syncthreads();
  float total = red[0];
  int cnt = fl[0] + fl[1] + fl[2] + fl[3];
  scn[t] = cnt;
  __syncthreads();
  for (int off = 1; off < 1024; off <<= 1) {
    int a = scn[t];
    int b = (t >= off) ? scn[t - off] : 0;
    __syncthreads();
    scn[t] = a + b;
    __syncthreads();
  }
  int p = scn[t] - cnt;
#pragma unroll
  for (int i = 0; i < 4; ++i) {
    if (fl[i]) {
      rows[batch * KSEL + p] = t * 4 + i;
      rwv[batch * KSEL + p]  = ex[i] / total;
      slot[batch * SEQ + t * 4 + i] = batch * KSEL + p;
      ++p;
    }
  }
}

// ---- fused: selected rows -> bf16 Xc; unselected rows -> out (= x) ----
__global__ void gather_copy_kernel(const float* __restrict__ x, const int* __restrict__ sel,
                                   const int* __restrict__ slot,
                                   unsigned short* __restrict__ Xc, float* __restrict__ out) {
  int tokg = blockIdx.x;           // 0..16383
  const float4* src = (const float4*)(x + (size_t)tokg * DIM);
  int t = threadIdx.x;             // 256
  float4 v = src[t];
  if (sel[tokg]) {
    ushort4 o;
    o.x = f2bf(v.x); o.y = f2bf(v.y); o.z = f2bf(v.z); o.w = f2bf(v.w);
    ((ushort4*)(Xc + (size_t)slot[tokg] * DIM))[t] = o;
  } else {
    ((float4*)(out + (size_t)tokg * DIM))[t] = v;
  }
}

// ---- transpose + cast f32 [R][C] -> bf16 [C][R] ----
__global__ void transpose_cast(const float* __restrict__ W, unsigned short* __restrict__ Wt,
                               int R, int C) {
  __shared__ float tl[32][33];
  int c0 = blockIdx.x * 32;
  int r0 = blockIdx.y * 32;
  int tx = threadIdx.x, ty = threadIdx.y;
#pragma unroll
  for (int i = 0; i < 4; ++i)
    tl[ty + i * 8][tx] = W[(size_t)(r0 + ty + i * 8) * C + c0 + tx];
  __syncthreads();
#pragma unroll
  for (int i = 0; i < 4; ++i)
    Wt[(size_t)(c0 + ty + i * 8) * R + r0 + tx] = f2bf(tl[tx][ty + i * 8]);
}

// ==== m97-structure GEMM: 128x128 tile, BK=32, single-buffer 16KB LDS ====
// 256 threads = 4 waves (2M x 2N), wave tile 64x64, acc[4][4].
// Loop: stage (2 GLD16/thread/matrix) -> syncthreads -> 16 MFMA -> syncthreads.
// ~3 blocks/CU resident: cross-block overlap hides the per-tile drain (m114).
// LDS swizzle on 64B rows: slot ^= (row&3)^((row>>2)&3) (<=2-way banks, free),
// applied via pre-swizzled global source + swizzled ds_read.
// EPI=1: H = bf16(gelu(acc+b1));  EPI=2: out[scatter] = x + rw*(acc+b2)
template <int EPI>
__global__ __launch_bounds__(256)
void gemm9(const unsigned short* __restrict__ A, const unsigned short* __restrict__ Bt,
           int M, int N, int K,
           const float* __restrict__ bias,
           unsigned short* __restrict__ Hout,
           const float* __restrict__ x,
           const int* __restrict__ rows,
           const float* __restrict__ rwv,
           float* __restrict__ out) {
  __shared__ __align__(16) unsigned short As[128 * 32];
  __shared__ __align__(16) unsigned short Bs[128 * 32];
  const int t = threadIdx.x;
  const int lane = t & 63;
  const int wid = t >> 6;
  const int wm = wid >> 1;               // 0..1
  const int wn = wid & 1;                // 0..1

  // XCD-aware bijective swizzle (gridDim.x % 8 == 0 by construction)
  const int nwg = gridDim.x;
  const int qq = nwg >> 3;
  const int nid = (blockIdx.x & 7) * qq + (blockIdx.x >> 3);
  const int gx = N / 128;
  const int by = nid / gx;
  const int bx = nid - by * gx;
  const int bm0 = by * 128;
  const int bn0 = bx * 128;

  const size_t ldb = (size_t)K * 2;      // row bytes
  const char* Ab = (const char*)A + (size_t)bm0 * ldb;
  const char* Bb = (const char*)Bt + (size_t)bn0 * ldb;
  char* AsB = (char*)As;
  char* BsB = (char*)Bs;

  // staging positions: pos = t + i*256 (i=0,1); row = pos>>2, dest slot = pos&3,
  // source slot = (pos&3) ^ swz(row), swz(row) = (row&3)^((row>>2)&3)
  const int pos0 = t, pos1 = t + 256;
  const int r0s = pos0 >> 2, r1s = pos1 >> 2;
  const int sl0 = (pos0 & 3) ^ ((r0s & 3) ^ ((r0s >> 2) & 3));
  const int sl1 = (pos1 & 3) ^ ((r1s & 3) ^ ((r1s >> 2) & 3));
  const size_t soff0 = (size_t)r0s * ldb + sl0 * 16;
  const size_t soff1 = (size_t)r1s * ldb + sl1 * 16;

  // fragment read offsets (swizzled): row-major [128][32] bf16, 64B rows
  // A-frag: row = wm*64 + i*16 + (lane&15); slot = (lane>>4) ^ swz(row)
  int arow[4], aoff[4], boff[4];
#pragma unroll
  for (int i = 0; i < 4; ++i) {
    int ra = wm * 64 + i * 16 + (lane & 15);
    int rb = wn * 64 + i * 16 + (lane & 15);
    aoff[i] = ra * 64 + (((lane >> 4) ^ ((ra & 3) ^ ((ra >> 2) & 3))) * 16);
    boff[i] = rb * 64 + (((lane >> 4) ^ ((rb & 3) ^ ((rb >> 2) & 3))) * 16);
  }

  f32x4_t acc[4][4];
  f32x4_t zero = {0.f, 0.f, 0.f, 0.f};
#pragma unroll
  for (int i = 0; i < 4; ++i)
#pragma unroll
    for (int j = 0; j < 4; ++j) acc[i][j] = zero;

  for (int k0 = 0; k0 < K; k0 += 32) {
    const size_t kb = (size_t)k0 * 2;
    GLD16(Ab + kb + soff0, AsB + pos0 * 16);
    GLD16(Ab + kb + soff1, AsB + pos1 * 16);
    GLD16(Bb + kb + soff0, BsB + pos0 * 16);
    GLD16(Bb + kb + soff1, BsB + pos1 * 16);
    __syncthreads();
    bf16x8_t af[4], bfr[4];
#pragma unroll
    for (int i = 0; i < 4; ++i) af[i]  = *(const bf16x8_t*)(AsB + aoff[i]);
#pragma unroll
    for (int j = 0; j < 4; ++j) bfr[j] = *(const bf16x8_t*)(BsB + boff[j]);
#pragma unroll
    for (int i = 0; i < 4; ++i)
#pragma unroll
      for (int j = 0; j < 4; ++j)
        acc[i][j] = __builtin_amdgcn_mfma_f32_16x16x32_bf16(af[i], bfr[j], acc[i][j], 0, 0, 0);
    __syncthreads();
  }

  // epilogue  (C/D: row = (lane>>4)*4 + qi (M), col = lane&15 (N))
  const int rb = (lane >> 4) * 4;
  const int cc = lane & 15;
#pragma unroll
  for (int i = 0; i < 4; ++i) {
#pragma unroll
    for (int qi = 0; qi < 4; ++qi) {
      int grow = bm0 + wm * 64 + i * 16 + rb + qi;
      if (EPI == 1) {
#pragma unroll
        for (int j = 0; j < 4; ++j) {
          int gcol = bn0 + wn * 64 + j * 16 + cc;
          float v = acc[i][j][qi] + bias[gcol];
          float cp = 0.7978845608028654f * (v + 0.044715f * v * v * v);
          float g = v / (1.f + __expf(-2.f * cp));   // tanh-approx gelu
          Hout[(size_t)grow * N + gcol] = f2bf(g);
        }
      } else {
        int batch = grow >> 11;
        int tok = rows[grow];
        float rw = rwv[grow];
        size_t obase = ((size_t)(batch * SEQ + tok)) * DIM;
#pragma unroll
        for (int j = 0; j < 4; ++j) {
          int gcol = bn0 + wn * 64 + j * 16 + cc;
          float v = acc[i][j][qi] + bias[gcol];
          out[obase + gcol] = x[obase + gcol] + rw * v;
        }
      }
    }
  }
}

// ---- aux BCE loss reduction ----
__global__ void aux_kernel(const float* __restrict__ logits, const int* __restrict__ sel,
                           float* __restrict__ out, int out_size) {
  __shared__ float red[16];
  int t = threadIdx.x;
  float sum = 0.f;
  for (int i = t; i < NTOK; i += 1024) {
    float l = logits[i];
    float tgt = sel[i] ? 1.f : 0.f;
    sum += fmaxf(l, 0.f) - l * tgt + log1pf(expf(-fabsf(l)));
  }
#pragma unroll
  for (int off = 32; off > 0; off >>= 1) sum += __shfl_down(sum, off);
  if ((t & 63) == 0) red[t >> 6] = sum;
  __syncthreads();
  if (t == 0) {
    float v = 0.f;
    for (int i = 0; i < 16; ++i) v += red[i];
    out[out_size - 1] = v / (float)NTOK;
  }
}

extern "C" void kernel_launch(void* const* d_in, const int* in_sizes, int n_in,
                              void* d_out, int out_size, void* d_ws, size_t ws_size,
                              hipStream_t stream) {
  const float* x  = (const float*)d_in[0];
  // d_in[1] = attention_mask (unused by reference)
  const float* Wr = (const float*)d_in[2];
  const float* br = (const float*)d_in[3];
  const float* W1 = (const float*)d_in[4];
  const float* b1 = (const float*)d_in[5];
  const float* W2 = (const float*)d_in[6];
  const float* b2 = (const float*)d_in[7];
  float* out = (float*)d_out;

  char* ws = (char*)d_ws;
  float* logits = (float*)(ws);
  float* scores = (float*)(ws + 65536);
  int*   sel    = (int*)(ws + 131072);
  int*   rows   = (int*)(ws + 196608);
  float* rwv    = (float*)(ws + 229376);
  int*   slot   = (int*)(ws + 262144);
  unsigned short* W1t = (unsigned short*)(ws + 327680);
  unsigned short* W2t = (unsigned short*)(ws + 327680 + 8388608);
  unsigned short* Xc  = (unsigned short*)(ws + 327680 + 2 * 8388608);
  unsigned short* H   = (unsigned short*)(ws + 327680 + 2 * 8388608 + 16777216);

  transpose_cast<<<dim3(DFF / 32, DIM / 32), dim3(32, 8), 0, stream>>>(W1, W1t, DIM, DFF);
  transpose_cast<<<dim3(DIM / 32, DFF / 32), dim3(32, 8), 0, stream>>>(W2, W2t, DFF, DIM);
  router_kernel<<<NTOK / 4, 256, 0, stream>>>(x, Wr, br, logits, scores);
  rank_kernel<<<NTOK / 16, 256, 0, stream>>>(scores, sel);
  pack_kernel<<<NB, 1024, 0, stream>>>(scores, sel, rows, rwv, slot);
  gather_copy_kernel<<<NTOK, 256, 0, stream>>>(x, sel, slot, Xc, out);
  gemm9<1><<<(MR / 128) * (DFF / 128), 256, 0, stream>>>(
      Xc, W1t, MR, DFF, DIM, b1, H, nullptr, nullptr, nullptr, nullptr);
  gemm9<2><<<(MR / 128) * (DIM / 128), 256, 0, stream>>>(
      H, W2t, MR, DIM, DFF, b2, nullptr, x, rows, rwv, out);
  aux_kernel<<<1, 1024, 0, stream>>>(logits, sel, out, out_size);
}

// Round 10
// 280.837 us; speedup vs baseline: 1.1256x; 1.1256x over previous
//
#include <hip/hip_runtime.h>

#define NB 4
#define SEQ 4096
#define DIM 1024
#define DFF 4096
#define KSEL 2048
#define NTOK (NB * SEQ)   // 16384
#define MR (NB * KSEL)    // 8192

typedef float f32x4_t __attribute__((ext_vector_type(4)));
typedef __bf16 bf16x8_t __attribute__((ext_vector_type(8)));

__device__ __forceinline__ unsigned short f2bf(float f) {
  union { float f; unsigned u; } v; v.f = f;
  unsigned r = v.u + 0x7fffu + ((v.u >> 16) & 1u);  // RNE
  return (unsigned short)(r >> 16);
}

#define GLD16(g, l) __builtin_amdgcn_global_load_lds( \
    (const __attribute__((address_space(1))) void*)(g), \
    (__attribute__((address_space(3))) void*)(l), 16, 0, 0)

// ---- router GEMV (one wave per row) ----
__global__ void router_kernel(const float* __restrict__ x, const float* __restrict__ Wr,
                              const float* __restrict__ br,
                              float* __restrict__ logits, float* __restrict__ scores) {
  int lane = threadIdx.x & 63;
  int wid  = threadIdx.x >> 6;
  int row  = blockIdx.x * 4 + wid;            // 0..16383
  const float4* xr = (const float4*)(x + (size_t)row * DIM);
  const float4* w4 = (const float4*)Wr;
  float sum = 0.f;
#pragma unroll
  for (int i = 0; i < 4; ++i) {
    float4 a = xr[lane + i * 64];
    float4 w = w4[lane + i * 64];
    sum += a.x * w.x + a.y * w.y + a.z * w.z + a.w * w.w;
  }
#pragma unroll
  for (int off = 32; off > 0; off >>= 1) sum += __shfl_down(sum, off);
  if (lane == 0) {
    float l = sum + br[0];
    logits[row] = l;
    scores[row] = 1.f / (1.f + expf(-l));
  }
}

// ---- exact top-k via rank counting (matches jax.lax.top_k tie-break) ----
__global__ void rank_kernel(const float* __restrict__ scores, int* __restrict__ sel) {
  __shared__ float s_sc[SEQ];
  int batch = blockIdx.x >> 8;        // 256 blocks per batch
  int chunk = blockIdx.x & 255;
  int t = threadIdx.x;                // 256
  const float4* sb4 = (const float4*)(scores + batch * SEQ);
  float4* ls4 = (float4*)s_sc;
#pragma unroll
  for (int i = 0; i < 4; ++i) ls4[t + i * 256] = sb4[t + i * 256];
  __syncthreads();
  int tok = chunk * 16 + (t >> 4);    // token this thread contributes to
  int sg  = t & 15;                   // score segment 0..15 (256 scores each)
  float s = s_sc[tok];
  const float4* seg = ls4 + sg * 64;
  int jbase = sg * 256;
  int rank = 0;
#pragma unroll 4
  for (int j4 = 0; j4 < 64; ++j4) {
    float4 v = seg[j4];
    int j = jbase + j4 * 4;
    rank += (v.x > s || (v.x == s && j     < tok)) ? 1 : 0;
    rank += (v.y > s || (v.y == s && j + 1 < tok)) ? 1 : 0;
    rank += (v.z > s || (v.z == s && j + 2 < tok)) ? 1 : 0;
    rank += (v.w > s || (v.w == s && j + 3 < tok)) ? 1 : 0;
  }
#pragma unroll
  for (int off = 8; off > 0; off >>= 1) rank += __shfl_down(rank, off, 16);
  if (sg == 0) sel[batch * SEQ + tok] = (rank < KSEL) ? 1 : 0;
}

// ---- per-batch: softmax over selected scores + prefix-sum compaction ----
__global__ void pack_kernel(const float* __restrict__ scores, const int* __restrict__ sel,
                            int* __restrict__ rows, float* __restrict__ rwv,
                            int* __restrict__ slot) {
  __shared__ float red[16];
  __shared__ int scn[1024];
  int batch = blockIdx.x;
  int t = threadIdx.x;
  const float* sb = scores + batch * SEQ;
  const int* fb = sel + batch * SEQ;
  float sc[4]; int fl[4];
#pragma unroll
  for (int i = 0; i < 4; ++i) { sc[i] = sb[t * 4 + i]; fl[i] = fb[t * 4 + i]; }
  float m = fmaxf(fmaxf(sc[0], sc[1]), fmaxf(sc[2], sc[3]));
#pragma unroll
  for (int off = 32; off > 0; off >>= 1) m = fmaxf(m, __shfl_down(m, off));
  if ((t & 63) == 0) red[t >> 6] = m;
  __syncthreads();
  if (t == 0) { float v = red[0]; for (int i = 1; i < 16; ++i) v = fmaxf(v, red[i]); red[0] = v; }
  __syncthreads();
  m = red[0];
  __syncthreads();
  float ex[4]; float esum = 0.f;
#pragma unroll
  for (int i = 0; i < 4; ++i) { ex[i] = expf(sc[i] - m); if (fl[i]) esum += ex[i]; }
#pragma unroll
  for (int off = 32; off > 0; off >>= 1) esum += __shfl_down(esum, off);
  if ((t & 63) == 0) red[t >> 6] = esum;
  __syncthreads();
  if (t == 0) { float v = 0.f; for (int i = 0; i < 16; ++i) v += red[i]; red[0] = v; }
  __syncthreads();
  float total = red[0];
  int cnt = fl[0] + fl[1] + fl[2] + fl[3];
  scn[t] = cnt;
  __syncthreads();
  for (int off = 1; off < 1024; off <<= 1) {
    int a = scn[t];
    int b = (t >= off) ? scn[t - off] : 0;
    __syncthreads();
    scn[t] = a + b;
    __syncthreads();
  }
  int p = scn[t] - cnt;
#pragma unroll
  for (int i = 0; i < 4; ++i) {
    if (fl[i]) {
      rows[batch * KSEL + p] = t * 4 + i;
      rwv[batch * KSEL + p]  = ex[i] / total;
      slot[batch * SEQ + t * 4 + i] = batch * KSEL + p;
      ++p;
    }
  }
}

// ---- fused: selected rows -> bf16 Xc; unselected rows -> out (= x) ----
__global__ void gather_copy_kernel(const float* __restrict__ x, const int* __restrict__ sel,
                                   const int* __restrict__ slot,
                                   unsigned short* __restrict__ Xc, float* __restrict__ out) {
  int tokg = blockIdx.x;           // 0..16383
  const float4* src = (const float4*)(x + (size_t)tokg * DIM);
  int t = threadIdx.x;             // 256
  float4 v = src[t];
  if (sel[tokg]) {
    ushort4 o;
    o.x = f2bf(v.x); o.y = f2bf(v.y); o.z = f2bf(v.z); o.w = f2bf(v.w);
    ((ushort4*)(Xc + (size_t)slot[tokg] * DIM))[t] = o;
  } else {
    ((float4*)(out + (size_t)tokg * DIM))[t] = v;
  }
}

// ---- fused transpose+cast for BOTH weight matrices in one launch ----
__global__ void transpose_cast2(const float* __restrict__ W1, unsigned short* __restrict__ W1t,
                                const float* __restrict__ W2, unsigned short* __restrict__ W2t) {
  __shared__ float tl[32][33];
  int bid = blockIdx.x;
  const float* W; unsigned short* Wt; int R, C, bx, by;
  if (bid < 4096) { W = W1; Wt = W1t; R = DIM; C = DFF; bx = bid & 127; by = bid >> 7; }
  else { bid -= 4096; W = W2; Wt = W2t; R = DFF; C = DIM; bx = bid & 31; by = bid >> 5; }
  int c0 = bx * 32;
  int r0 = by * 32;
  int tx = threadIdx.x, ty = threadIdx.y;
#pragma unroll
  for (int i = 0; i < 4; ++i)
    tl[ty + i * 8][tx] = W[(size_t)(r0 + ty + i * 8) * C + c0 + tx];
  __syncthreads();
#pragma unroll
  for (int i = 0; i < 4; ++i)
    Wt[(size_t)(c0 + ty + i * 8) * R + r0 + tx] = f2bf(tl[tx][ty + i * 8]);
}

// ==== 256x128 bf16 GEMM: m201 lockstep phases + DEPTH-2 prefetch (3 buf) ====
// BM=256, BN=128, BK=64, 512 threads = 8 waves (2M x 4N), wave tile 128x32.
// 3 LDS buffers (48 KB each = 144 KB). Tile t reads buf t%3; tile t+2's 6
// loads are spread across tile t's 4 phases into buf (t+2)%3 (never live).
// Per-tile phases (full lockstep, m201 template):
//   p0: rd A0(8)+B0(2); 2 gld; bar; lgkm0; prio1 MFMA(A0xB0) prio0; bar
//   p1: rd A1(8)       ; 2 gld; bar; lgkm0; prio1 MFMA(A1xB0) prio0; bar
//   p2: rd B1(2)       ; 1 gld; bar; lgkm0; prio1 MFMA(A0xB1) prio0; bar
//   p3:                ; 1 gld; bar;        prio1 MFMA(A1xB1) prio0;
//       vmcnt(6) [tile t+1 complete, issued a FULL TILE earlier; t+2 in
//       flight -- never drains to 0 until the peeled end]; bar
// LDS XOR-swizzle byte^=((row&7)<<4) via pre-swizzled global source (0 conf).
// EPI=1: H = bf16(gelu(acc+b1));  EPI=2: out[scatter] = x + rw*(acc+b2)
template <int EPI>
__global__ __launch_bounds__(512, 1)
void gemm10(const unsigned short* __restrict__ A, const unsigned short* __restrict__ Bt,
            int M, int N, int K,
            const float* __restrict__ bias,
            unsigned short* __restrict__ Hout,
            const float* __restrict__ x,
            const int* __restrict__ rows,
            const float* __restrict__ rwv,
            float* __restrict__ out) {
  constexpr int BN = 128;
  constexpr int ABY = 256 * 128;           // 32 KB
  constexpr int BBY = BN * 128;            // 16 KB
  constexpr int TB = ABY + BBY;            // 48 KB
  __shared__ __align__(16) char lds[3 * TB];   // 144 KB

  const int t = threadIdx.x;
  const int lane = t & 63;
  const int wid = t >> 6;
  const int wm = wid >> 2;                 // 0..1
  const int wn = wid & 3;                  // 0..3

  // XCD-aware bijective swizzle (gridDim.x % 8 == 0 by construction)
  const int nwg = gridDim.x;
  const int qq = nwg >> 3;
  const int nid = (blockIdx.x & 7) * qq + (blockIdx.x >> 3);
  const int gx = N / BN;
  const int by = nid / gx;
  const int bx = nid - by * gx;
  const int bm0 = by * 256;
  const int bn0 = bx * BN;

  const size_t ldb = (size_t)K * 2;        // row bytes for A and Bt
  const char* Ab = (const char*)A;
  const char* Bb = (const char*)Bt;

  // staging: thread t covers LDS bytes [t*16, t*16+16) of each 64-row chunk;
  // chunk row = t>>3, dest slot = t&7, source slot = (t&7)^(row&7)
  const int srow = t >> 3;
  const size_t stage_off = (size_t)srow * ldb + (size_t)((((t & 7) ^ (srow & 7)) * 16));

  // ds_read fragment offsets (swizzled)
  const int cbs0 = (((lane >> 4) * 16)     ) ^ ((lane & 7) << 4);  // kk=0
  const int cbs1 = (64 + (lane >> 4) * 16) ^ ((lane & 7) << 4);    // kk=1

  f32x4_t acc[8][2];
  f32x4_t zero = {0.f, 0.f, 0.f, 0.f};
#pragma unroll
  for (int i = 0; i < 8; ++i) { acc[i][0] = zero; acc[i][1] = zero; }

  const int NT = K / 64;

  auto gldB = [&](int b, int kt, int c) {
    const char* bbase = Bb + (size_t)bn0 * ldb + (size_t)kt * 128 + stage_off;
    GLD16(bbase + (size_t)(c * 64) * ldb, lds + b * TB + ABY + t * 16 + c * 8192);
  };
  auto gldA = [&](int b, int kt, int c) {
    const char* abase = Ab + (size_t)bm0 * ldb + (size_t)kt * 128 + stage_off;
    GLD16(abase + (size_t)(c * 64) * ldb, lds + b * TB + t * 16 + c * 8192);
  };
  auto stage_all = [&](int b, int kt) {
    gldB(b, kt, 0); gldB(b, kt, 1);
#pragma unroll
    for (int c = 0; c < 4; ++c) gldA(b, kt, c);
  };

  bf16x8_t am[2][4][2];       // both A halves live across the tile
  bf16x8_t bq[2][2];          // both B frags live across the tile

  auto rdA = [&](const char* Al, int qm) {
#pragma unroll
    for (int mi = 0; mi < 4; ++mi) {
      int row = wm * 128 + qm * 64 + mi * 16 + (lane & 15);
      const char* ap = Al + row * 128;
      am[qm][mi][0] = *(const bf16x8_t*)(ap + cbs0);
      am[qm][mi][1] = *(const bf16x8_t*)(ap + cbs1);
    }
  };
  auto rdB = [&](const char* Bl, int qn) {
    int row = wn * 32 + qn * 16 + (lane & 15);
    const char* bp = Bl + row * 128;
    bq[qn][0] = *(const bf16x8_t*)(bp + cbs0);
    bq[qn][1] = *(const bf16x8_t*)(bp + cbs1);
  };
  auto domfma = [&](int qm, int qn) {
    __builtin_amdgcn_s_setprio(1);
#pragma unroll
    for (int mi = 0; mi < 4; ++mi) {
      acc[qm * 4 + mi][qn] = __builtin_amdgcn_mfma_f32_16x16x32_bf16(
          am[qm][mi][0], bq[qn][0], acc[qm * 4 + mi][qn], 0, 0, 0);
      acc[qm * 4 + mi][qn] = __builtin_amdgcn_mfma_f32_16x16x32_bf16(
          am[qm][mi][1], bq[qn][1], acc[qm * 4 + mi][qn], 0, 0, 0);
    }
    __builtin_amdgcn_s_setprio(0);
  };

  // prologue: stage tiles 0 and 1; tile 0 must be complete (tile 1 in flight)
  stage_all(0, 0);
  if (NT > 1) stage_all(1, 1);
  if (NT > 1) asm volatile("s_waitcnt vmcnt(6)" ::: "memory");
  else        asm volatile("s_waitcnt vmcnt(0)" ::: "memory");
  __builtin_amdgcn_s_barrier();
  __builtin_amdgcn_sched_barrier(0);

  int b = 0, b2 = 2;
  for (int kt = 0; kt < NT; ++kt) {
    const char* Al = lds + b * TB;
    const char* Bl = Al + ABY;
    const bool sn2 = (kt + 2 < NT);

    // ---- p0: A0 x B0 ----
    rdA(Al, 0);
    rdB(Bl, 0);
    if (sn2) { gldB(b2, kt + 2, 0); gldB(b2, kt + 2, 1); }
    __builtin_amdgcn_s_barrier();
    asm volatile("s_waitcnt lgkmcnt(0)" ::: "memory");
    __builtin_amdgcn_sched_barrier(0);
    domfma(0, 0);
    __builtin_amdgcn_s_barrier();
    // ---- p1: A1 x B0 ----
    rdA(Al, 1);
    if (sn2) { gldA(b2, kt + 2, 0); gldA(b2, kt + 2, 1); }
    __builtin_amdgcn_s_barrier();
    asm volatile("s_waitcnt lgkmcnt(0)" ::: "memory");
    __builtin_amdgcn_sched_barrier(0);
    domfma(1, 0);
    __builtin_amdgcn_s_barrier();
    // ---- p2: A0 x B1 ----
    rdB(Bl, 1);
    if (sn2) gldA(b2, kt + 2, 2);
    __builtin_amdgcn_s_barrier();
    asm volatile("s_waitcnt lgkmcnt(0)" ::: "memory");
    __builtin_amdgcn_sched_barrier(0);
    domfma(0, 1);
    __builtin_amdgcn_s_barrier();
    // ---- p3: A1 x B1 ----
    if (sn2) gldA(b2, kt + 2, 3);
    domfma(1, 1);
    // boundary: tile kt+1 (issued a full tile ago) must be complete;
    // tile kt+2's 6 loads stay in flight. Never 0 until the end.
    if (sn2) asm volatile("s_waitcnt vmcnt(6)" ::: "memory");
    else     asm volatile("s_waitcnt vmcnt(0)" ::: "memory");
    __builtin_amdgcn_s_barrier();
    __builtin_amdgcn_sched_barrier(0);
    b = (b == 2) ? 0 : b + 1;
    b2 = (b2 == 2) ? 0 : b2 + 1;
  }

  // epilogue  (C/D: row = (lane>>4)*4 + qi (M), col = lane&15 (N))
  const int rb = (lane >> 4) * 4;
  const int cc = lane & 15;
  float bs[2];
  bs[0] = bias[bn0 + wn * 32 + cc];
  bs[1] = bias[bn0 + wn * 32 + 16 + cc];
#pragma unroll
  for (int m = 0; m < 8; ++m) {
#pragma unroll
    for (int qi = 0; qi < 4; ++qi) {
      int grow = bm0 + wm * 128 + m * 16 + rb + qi;
      if (EPI == 1) {
#pragma unroll
        for (int n = 0; n < 2; ++n) {
          int gcol = bn0 + wn * 32 + n * 16 + cc;
          float v = acc[m][n][qi] + bs[n];
          float cp = 0.7978845608028654f * (v + 0.044715f * v * v * v);
          float g = v / (1.f + __expf(-2.f * cp));   // tanh-approx gelu
          Hout[(size_t)grow * N + gcol] = f2bf(g);
        }
      } else {
        int batch = grow >> 11;
        int tok = rows[grow];
        float rw = rwv[grow];
        size_t obase = ((size_t)(batch * SEQ + tok)) * DIM;
#pragma unroll
        for (int n = 0; n < 2; ++n) {
          int gcol = bn0 + wn * 32 + n * 16 + cc;
          float v = acc[m][n][qi] + bs[n];
          out[obase + gcol] = x[obase + gcol] + rw * v;
        }
      }
    }
  }
}

// ---- aux BCE loss reduction ----
__global__ void aux_kernel(const float* __restrict__ logits, const int* __restrict__ sel,
                           float* __restrict__ out, int out_size) {
  __shared__ float red[16];
  int t = threadIdx.x;
  float sum = 0.f;
  for (int i = t; i < NTOK; i += 1024) {
    float l = logits[i];
    float tgt = sel[i] ? 1.f : 0.f;
    sum += fmaxf(l, 0.f) - l * tgt + log1pf(expf(-fabsf(l)));
  }
#pragma unroll
  for (int off = 32; off > 0; off >>= 1) sum += __shfl_down(sum, off);
  if ((t & 63) == 0) red[t >> 6] = sum;
  __syncthreads();
  if (t == 0) {
    float v = 0.f;
    for (int i = 0; i < 16; ++i) v += red[i];
    out[out_size - 1] = v / (float)NTOK;
  }
}

extern "C" void kernel_launch(void* const* d_in, const int* in_sizes, int n_in,
                              void* d_out, int out_size, void* d_ws, size_t ws_size,
                              hipStream_t stream) {
  const float* x  = (const float*)d_in[0];
  // d_in[1] = attention_mask (unused by reference)
  const float* Wr = (const float*)d_in[2];
  const float* br = (const float*)d_in[3];
  const float* W1 = (const float*)d_in[4];
  const float* b1 = (const float*)d_in[5];
  const float* W2 = (const float*)d_in[6];
  const float* b2 = (const float*)d_in[7];
  float* out = (float*)d_out;

  char* ws = (char*)d_ws;
  float* logits = (float*)(ws);
  float* scores = (float*)(ws + 65536);
  int*   sel    = (int*)(ws + 131072);
  int*   rows   = (int*)(ws + 196608);
  float* rwv    = (float*)(ws + 229376);
  int*   slot   = (int*)(ws + 262144);
  unsigned short* W1t = (unsigned short*)(ws + 327680);
  unsigned short* W2t = (unsigned short*)(ws + 327680 + 8388608);
  unsigned short* Xc  = (unsigned short*)(ws + 327680 + 2 * 8388608);
  unsigned short* H   = (unsigned short*)(ws + 327680 + 2 * 8388608 + 16777216);

  transpose_cast2<<<8192, dim3(32, 8), 0, stream>>>(W1, W1t, W2, W2t);
  router_kernel<<<NTOK / 4, 256, 0, stream>>>(x, Wr, br, logits, scores);
  rank_kernel<<<NTOK / 16, 256, 0, stream>>>(scores, sel);
  pack_kernel<<<NB, 1024, 0, stream>>>(scores, sel, rows, rwv, slot);
  gather_copy_kernel<<<NTOK, 256, 0, stream>>>(x, sel, slot, Xc, out);
  gemm10<1><<<(MR / 256) * (DFF / 128), 512, 0, stream>>>(
      Xc, W1t, MR, DFF, DIM, b1, H, nullptr, nullptr, nullptr, nullptr);
  gemm10<2><<<(MR / 256) * (DIM / 128), 512, 0, stream>>>(
      H, W2t, MR, DIM, DFF, b2, nullptr, x, rows, rwv, out);
  aux_kernel<<<1, 1024, 0, stream>>>(logits, sel, out, out_size);
}

// Round 11
// 242.923 us; speedup vs baseline: 1.3013x; 1.1561x over previous
//
#include <hip/hip_runtime.h>

#define NB 4
#define SEQ 4096
#define DIM 1024
#define DFF 4096
#define KSEL 2048
#define NTOK (NB * SEQ)   // 16384
#define MR (NB * KSEL)    // 8192

typedef float f32x4_t __attribute__((ext_vector_type(4)));
typedef unsigned long u64_t;

__device__ __forceinline__ unsigned short f2bf(float f) {
  union { float f; unsigned u; } v; v.f = f;
  unsigned r = v.u + 0x7fffu + ((v.u >> 16) & 1u);  // RNE
  return (unsigned short)(r >> 16);
}

// HW f32->fp8 e4m3 (OCP, RNE, saturating): pack 2 floats into 2 bytes
__device__ __forceinline__ unsigned char f2fp8(float f) {
  return (unsigned char)(__builtin_amdgcn_cvt_pk_fp8_f32(f, f, 0, false) & 0xff);
}

#define GLD16(g, l) __builtin_amdgcn_global_load_lds( \
    (const __attribute__((address_space(1))) void*)(g), \
    (__attribute__((address_space(3))) void*)(l), 16, 0, 0)

// ---- router GEMV (one wave per row) ----
__global__ void router_kernel(const float* __restrict__ x, const float* __restrict__ Wr,
                              const float* __restrict__ br,
                              float* __restrict__ logits, float* __restrict__ scores) {
  int lane = threadIdx.x & 63;
  int wid  = threadIdx.x >> 6;
  int row  = blockIdx.x * 4 + wid;            // 0..16383
  const float4* xr = (const float4*)(x + (size_t)row * DIM);
  const float4* w4 = (const float4*)Wr;
  float sum = 0.f;
#pragma unroll
  for (int i = 0; i < 4; ++i) {
    float4 a = xr[lane + i * 64];
    float4 w = w4[lane + i * 64];
    sum += a.x * w.x + a.y * w.y + a.z * w.z + a.w * w.w;
  }
#pragma unroll
  for (int off = 32; off > 0; off >>= 1) sum += __shfl_down(sum, off);
  if (lane == 0) {
    float l = sum + br[0];
    logits[row] = l;
    scores[row] = 1.f / (1.f + expf(-l));
  }
}

// ---- exact top-k via rank counting (matches jax.lax.top_k tie-break) ----
__global__ void rank_kernel(const float* __restrict__ scores, int* __restrict__ sel) {
  __shared__ float s_sc[SEQ];
  int batch = blockIdx.x >> 8;        // 256 blocks per batch
  int chunk = blockIdx.x & 255;
  int t = threadIdx.x;                // 256
  const float4* sb4 = (const float4*)(scores + batch * SEQ);
  float4* ls4 = (float4*)s_sc;
#pragma unroll
  for (int i = 0; i < 4; ++i) ls4[t + i * 256] = sb4[t + i * 256];
  __syncthreads();
  int tok = chunk * 16 + (t >> 4);    // token this thread contributes to
  int sg  = t & 15;                   // score segment 0..15 (256 scores each)
  float s = s_sc[tok];
  const float4* seg = ls4 + sg * 64;
  int jbase = sg * 256;
  int rank = 0;
#pragma unroll 4
  for (int j4 = 0; j4 < 64; ++j4) {
    float4 v = seg[j4];
    int j = jbase + j4 * 4;
    rank += (v.x > s || (v.x == s && j     < tok)) ? 1 : 0;
    rank += (v.y > s || (v.y == s && j + 1 < tok)) ? 1 : 0;
    rank += (v.z > s || (v.z == s && j + 2 < tok)) ? 1 : 0;
    rank += (v.w > s || (v.w == s && j + 3 < tok)) ? 1 : 0;
  }
#pragma unroll
  for (int off = 8; off > 0; off >>= 1) rank += __shfl_down(rank, off, 16);
  if (sg == 0) sel[batch * SEQ + tok] = (rank < KSEL) ? 1 : 0;
}

// ---- per-batch: softmax over selected scores + prefix-sum compaction ----
__global__ void pack_kernel(const float* __restrict__ scores, const int* __restrict__ sel,
                            int* __restrict__ rows, float* __restrict__ rwv,
                            int* __restrict__ slot) {
  __shared__ float red[16];
  __shared__ int scn[1024];
  int batch = blockIdx.x;
  int t = threadIdx.x;
  const float* sb = scores + batch * SEQ;
  const int* fb = sel + batch * SEQ;
  float sc[4]; int fl[4];
#pragma unroll
  for (int i = 0; i < 4; ++i) { sc[i] = sb[t * 4 + i]; fl[i] = fb[t * 4 + i]; }
  float m = fmaxf(fmaxf(sc[0], sc[1]), fmaxf(sc[2], sc[3]));
#pragma unroll
  for (int off = 32; off > 0; off >>= 1) m = fmaxf(m, __shfl_down(m, off));
  if ((t & 63) == 0) red[t >> 6] = m;
  __syncthreads();
  if (t == 0) { float v = red[0]; for (int i = 1; i < 16; ++i) v = fmaxf(v, red[i]); red[0] = v; }
  __syncthreads();
  m = red[0];
  __syncthreads();
  float ex[4]; float esum = 0.f;
#pragma unroll
  for (int i = 0; i < 4; ++i) { ex[i] = expf(sc[i] - m); if (fl[i]) esum += ex[i]; }
#pragma unroll
  for (int off = 32; off > 0; off >>= 1) esum += __shfl_down(esum, off);
  if ((t & 63) == 0) red[t >> 6] = esum;
  __syncthreads();
  if (t == 0) { float v = 0.f; for (int i = 0; i < 16; ++i) v += red[i]; red[0] = v; }
  __syncthreads();
  float total = red[0];
  int cnt = fl[0] + fl[1] + fl[2] + fl[3];
  scn[t] = cnt;
  __syncthreads();
  for (int off = 1; off < 1024; off <<= 1) {
    int a = scn[t];
    int b = (t >= off) ? scn[t - off] : 0;
    __syncthreads();
    scn[t] = a + b;
    __syncthreads();
  }
  int p = scn[t] - cnt;
#pragma unroll
  for (int i = 0; i < 4; ++i) {
    if (fl[i]) {
      rows[batch * KSEL + p] = t * 4 + i;
      rwv[batch * KSEL + p]  = ex[i] / total;
      slot[batch * SEQ + t * 4 + i] = batch * KSEL + p;
      ++p;
    }
  }
}

// ---- fused: selected rows -> fp8 Xc; unselected rows -> out (= x) ----
__global__ void gather_copy_kernel(const float* __restrict__ x, const int* __restrict__ sel,
                                   const int* __restrict__ slot,
                                   unsigned char* __restrict__ Xc, float* __restrict__ out) {
  int tokg = blockIdx.x;           // 0..16383
  const float4* src = (const float4*)(x + (size_t)tokg * DIM);
  int t = threadIdx.x;             // 256
  float4 v = src[t];
  if (sel[tokg]) {
    unsigned lo = (unsigned)__builtin_amdgcn_cvt_pk_fp8_f32(v.x, v.y, 0, false);
    unsigned both = (unsigned)__builtin_amdgcn_cvt_pk_fp8_f32(v.z, v.w, (int)lo, true);
    ((unsigned*)(Xc + (size_t)slot[tokg] * DIM))[t] = both;
  } else {
    ((float4*)(out + (size_t)tokg * DIM))[t] = v;
  }
}

// ---- fused transpose+cast f32 -> fp8 (x16 scale) for both weights ----
__global__ void transpose_cast2(const float* __restrict__ W1, unsigned char* __restrict__ W1t,
                                const float* __restrict__ W2, unsigned char* __restrict__ W2t) {
  __shared__ float tl[32][33];
  int bid = blockIdx.x;
  const float* W; unsigned char* Wt; int R, C, bx, by;
  if (bid < 4096) { W = W1; Wt = W1t; R = DIM; C = DFF; bx = bid & 127; by = bid >> 7; }
  else { bid -= 4096; W = W2; Wt = W2t; R = DFF; C = DIM; bx = bid & 31; by = bid >> 5; }
  int c0 = bx * 32;
  int r0 = by * 32;
  int tx = threadIdx.x, ty = threadIdx.y;
#pragma unroll
  for (int i = 0; i < 4; ++i)
    tl[ty + i * 8][tx] = W[(size_t)(r0 + ty + i * 8) * C + c0 + tx];
  __syncthreads();
#pragma unroll
  for (int i = 0; i < 4; ++i)
    Wt[(size_t)(c0 + ty + i * 8) * R + r0 + tx] = f2fp8(16.f * tl[tx][ty + i * 8]);
}

// ==== 256xBN FP8 MFMA GEMM (R3-best structure, BK=128 fp8 = 128B rows) ====
// 512 threads = 8 waves (2M x 4N), wave tile 128 x BN/4, acc[8][NREP].
// Double-buffered LDS (2 x (32KB + BN/8 KB)); per tile 4 quadrant phases:
//   q0: rdB all (NREP*4 b64) + rdA strips01 + stage(t+1); bar; 32*NREP/4 MFMA; bar
//   q1: rdA strips23; bar; MFMA; midwait vmcnt(S) [all of tile t landed]; bar
//   q2/q3: rdA; bar; MFMA; [q3: boundary vmcnt(2) -> stage order B*,A0,A2,A1,A3
//          leaves only A1,A3 (strips 4-7, read at q2/q3 after midwait) in flight]
// LDS XOR-swizzle byte^=((row&7)<<4) via pre-swizzled global source (0 confl).
// W pre-scaled x16 (avoids e4m3 subnormals) -> epilogue multiplies acc by 1/16.
// EPI=1: H = fp8(gelu(acc/16+b1));  EPI=2: out[scatter] = x + rw*(acc/16+b2)
template <int BN, int EPI>
__global__ __launch_bounds__(512, 2)
void gemmf8(const unsigned char* __restrict__ A, const unsigned char* __restrict__ Bt,
            int M, int N, int K,
            const float* __restrict__ bias,
            unsigned char* __restrict__ Hout,
            const float* __restrict__ x,
            const int* __restrict__ rows,
            const float* __restrict__ rwv,
            float* __restrict__ out) {
  constexpr int NREP = BN / 64;            // B frags per wave per kk (4 or 2)
  constexpr int NBC  = BN / 64;            // B stage chunks (64 rows each)
  constexpr int S    = 4 + NBC;            // stage loads per thread per tile
  constexpr int ABY = 256 * 128;           // 32 KB
  constexpr int BBY = BN * 128;
  constexpr int TB = ABY + BBY;
  __shared__ __align__(16) char lds[2 * TB];

  const int t = threadIdx.x;
  const int lane = t & 63;
  const int wid = t >> 6;
  const int wm = wid >> 2;                 // 0..1
  const int wn = wid & 3;                  // 0..3

  // XCD-aware bijective swizzle (gridDim.x % 8 == 0 by construction)
  const int nwg = gridDim.x;
  const int qq = nwg >> 3;
  const int nid = (blockIdx.x & 7) * qq + (blockIdx.x >> 3);
  const int gx = N / BN;
  const int by = nid / gx;
  const int bx = nid - by * gx;
  const int bm0 = by * 256;
  const int bn0 = bx * BN;

  const size_t ldb = (size_t)K;            // row BYTES (fp8: 1 B/elem)
  const char* Ab = (const char*)A;
  const char* Bb = (const char*)Bt;

  // staging: thread t covers LDS bytes [t*16, t*16+16) of each 64-row chunk;
  // chunk row = t>>3, dest slot = t&7, source slot = (t&7)^(row&7)
  const int srow = t >> 3;
  const size_t stage_off = (size_t)srow * ldb + (size_t)((((t & 7) ^ (srow & 7)) * 16));

  // fragment byte offsets within a 128B row (swizzled), kk = 0..3 (K=32 each)
  const int arow0 = wm * 128 + (lane & 15);
  const int brow0 = wn * (BN / 4) + (lane & 15);
  int cbs[4];
#pragma unroll
  for (int kk = 0; kk < 4; ++kk)
    cbs[kk] = ((lane >> 4) * 8 + kk * 32) ^ ((lane & 7) << 4);

  f32x4_t acc[8][NREP];
  f32x4_t zero = {0.f, 0.f, 0.f, 0.f};
#pragma unroll
  for (int i = 0; i < 8; ++i)
#pragma unroll
    for (int j = 0; j < NREP; ++j) acc[i][j] = zero;

  const int NT = K / 128;

  // stage order: B0..B(NBC-1), A0, A2, A1, A3  (last two = strips 4-7, q2/q3)
  auto stage = [&](int b, int kt) {
    char* base = lds + b * TB;
    const char* bbase = Bb + (size_t)bn0 * ldb + (size_t)kt * 128 + stage_off;
#pragma unroll
    for (int c = 0; c < NBC; ++c)
      GLD16(bbase + (size_t)(c * 64) * ldb, base + ABY + t * 16 + c * 8192);
    const char* abase = Ab + (size_t)bm0 * ldb + (size_t)kt * 128 + stage_off;
    const int order[4] = {0, 2, 1, 3};
#pragma unroll
    for (int i = 0; i < 4; ++i) {
      int c = order[i];
      GLD16(abase + (size_t)(c * 64) * ldb, base + t * 16 + c * 8192);
    }
  };

  // prologue: stage tile 0; all but A1,A3 (strips 4-7) must land
  stage(0, 0);
  asm volatile("s_waitcnt vmcnt(2)" ::: "memory");
  __builtin_amdgcn_s_barrier();
  __builtin_amdgcn_sched_barrier(0);

  for (int kt = 0; kt < NT; ++kt) {
    const int b = kt & 1;
    const char* Al = lds + b * TB;
    const char* Bl = Al + ABY;
    const bool sn = (kt + 1 < NT);
    u64_t bq[NREP][4];
    u64_t am[2][4];

    auto rdA = [&](int q) {
#pragma unroll
      for (int mi = 0; mi < 2; ++mi) {
        const char* ap = Al + (arow0 + (2 * q + mi) * 16) * 128;
#pragma unroll
        for (int kk = 0; kk < 4; ++kk)
          am[mi][kk] = *(const u64_t*)(ap + cbs[kk]);
      }
    };
    auto domfma = [&](int q) {
      __builtin_amdgcn_s_setprio(1);
#pragma unroll
      for (int mi = 0; mi < 2; ++mi)
#pragma unroll
        for (int n = 0; n < NREP; ++n)
#pragma unroll
          for (int kk = 0; kk < 4; ++kk)
            acc[2 * q + mi][n] = __builtin_amdgcn_mfma_f32_16x16x32_fp8_fp8(
                (long)am[mi][kk], (long)bq[n][kk], acc[2 * q + mi][n], 0, 0, 0);
      __builtin_amdgcn_s_setprio(0);
    };

    // ---- q0 ----
#pragma unroll
    for (int n = 0; n < NREP; ++n) {
      const char* bp = Bl + (brow0 + n * 16) * 128;
#pragma unroll
      for (int kk = 0; kk < 4; ++kk)
        bq[n][kk] = *(const u64_t*)(bp + cbs[kk]);
    }
    rdA(0);
    if (sn) stage(b ^ 1, kt + 1);
    __builtin_amdgcn_s_barrier();
    domfma(0);
    __builtin_amdgcn_s_barrier();
    // ---- q1 ----
    rdA(1);
    __builtin_amdgcn_s_barrier();
    domfma(1);
    if (sn) {
      if constexpr (S == 8) asm volatile("s_waitcnt vmcnt(8)" ::: "memory");
      else                  asm volatile("s_waitcnt vmcnt(6)" ::: "memory");
    } else {
      asm volatile("s_waitcnt vmcnt(0)" ::: "memory");
    }
    __builtin_amdgcn_s_barrier();
    __builtin_amdgcn_sched_barrier(0);
    // ---- q2 ----
    rdA(2);
    __builtin_amdgcn_s_barrier();
    domfma(2);
    __builtin_amdgcn_s_barrier();
    // ---- q3 ----
    rdA(3);
    __builtin_amdgcn_s_barrier();
    domfma(3);
    if (sn) asm volatile("s_waitcnt vmcnt(2)" ::: "memory");
    __builtin_amdgcn_s_barrier();
    __builtin_amdgcn_sched_barrier(0);
  }

  // epilogue  (C/D: row = (lane>>4)*4 + qi (M), col = lane&15 (N))
  const int rb = (lane >> 4) * 4;
  const int cc = lane & 15;
  float bs[NREP];
#pragma unroll
  for (int n = 0; n < NREP; ++n)
    bs[n] = bias[bn0 + wn * (BN / 4) + n * 16 + cc];
#pragma unroll
  for (int m = 0; m < 8; ++m) {
#pragma unroll
    for (int qi = 0; qi < 4; ++qi) {
      int grow = bm0 + wm * 128 + m * 16 + rb + qi;
      if (EPI == 1) {
#pragma unroll
        for (int n = 0; n < NREP; ++n) {
          int gcol = bn0 + wn * (BN / 4) + n * 16 + cc;
          float v = acc[m][n][qi] * 0.0625f + bs[n];
          float cp = 0.7978845608028654f * (v + 0.044715f * v * v * v);
          float g = v / (1.f + __expf(-2.f * cp));   // tanh-approx gelu
          Hout[(size_t)grow * N + gcol] = f2fp8(g);
        }
      } else {
        int batch = grow >> 11;
        int tok = rows[grow];
        float rw = rwv[grow];
        size_t obase = ((size_t)(batch * SEQ + tok)) * DIM;
#pragma unroll
        for (int n = 0; n < NREP; ++n) {
          int gcol = bn0 + wn * (BN / 4) + n * 16 + cc;
          float v = acc[m][n][qi] * 0.0625f + bs[n];
          out[obase + gcol] = x[obase + gcol] + rw * v;
        }
      }
    }
  }
}

// ---- aux BCE loss reduction ----
__global__ void aux_kernel(const float* __restrict__ logits, const int* __restrict__ sel,
                           float* __restrict__ out, int out_size) {
  __shared__ float red[16];
  int t = threadIdx.x;
  float sum = 0.f;
  for (int i = t; i < NTOK; i += 1024) {
    float l = logits[i];
    float tgt = sel[i] ? 1.f : 0.f;
    sum += fmaxf(l, 0.f) - l * tgt + log1pf(expf(-fabsf(l)));
  }
#pragma unroll
  for (int off = 32; off > 0; off >>= 1) sum += __shfl_down(sum, off);
  if ((t & 63) == 0) red[t >> 6] = sum;
  __syncthreads();
  if (t == 0) {
    float v = 0.f;
    for (int i = 0; i < 16; ++i) v += red[i];
    out[out_size - 1] = v / (float)NTOK;
  }
}

extern "C" void kernel_launch(void* const* d_in, const int* in_sizes, int n_in,
                              void* d_out, int out_size, void* d_ws, size_t ws_size,
                              hipStream_t stream) {
  const float* x  = (const float*)d_in[0];
  // d_in[1] = attention_mask (unused by reference)
  const float* Wr = (const float*)d_in[2];
  const float* br = (const float*)d_in[3];
  const float* W1 = (const float*)d_in[4];
  const float* b1 = (const float*)d_in[5];
  const float* W2 = (const float*)d_in[6];
  const float* b2 = (const float*)d_in[7];
  float* out = (float*)d_out;

  char* ws = (char*)d_ws;
  float* logits = (float*)(ws);
  float* scores = (float*)(ws + 65536);
  int*   sel    = (int*)(ws + 131072);
  int*   rows   = (int*)(ws + 196608);
  float* rwv    = (float*)(ws + 229376);
  int*   slot   = (int*)(ws + 262144);
  unsigned char* W1t = (unsigned char*)(ws + 327680);                     // 4 MB
  unsigned char* W2t = (unsigned char*)(ws + 327680 + 4194304);           // 4 MB
  unsigned char* Xc  = (unsigned char*)(ws + 327680 + 2 * 4194304);       // 8 MB
  unsigned char* H   = (unsigned char*)(ws + 327680 + 2 * 4194304 + 8388608);  // 32 MB

  transpose_cast2<<<8192, dim3(32, 8), 0, stream>>>(W1, W1t, W2, W2t);
  router_kernel<<<NTOK / 4, 256, 0, stream>>>(x, Wr, br, logits, scores);
  rank_kernel<<<NTOK / 16, 256, 0, stream>>>(scores, sel);
  pack_kernel<<<NB, 1024, 0, stream>>>(scores, sel, rows, rwv, slot);
  gather_copy_kernel<<<NTOK, 256, 0, stream>>>(x, sel, slot, Xc, out);
  gemmf8<256, 1><<<(MR / 256) * (DFF / 256), 512, 0, stream>>>(
      Xc, W1t, MR, DFF, DIM, b1, H, nullptr, nullptr, nullptr, nullptr);
  gemmf8<128, 2><<<(MR / 256) * (DIM / 128), 512, 0, stream>>>(
      H, W2t, MR, DIM, DFF, b2, nullptr, x, rows, rwv, out);
  aux_kernel<<<1, 1024, 0, stream>>>(logits, sel, out, out_size);
}

// Round 12
// 229.802 us; speedup vs baseline: 1.3756x; 1.0571x over previous
//
#include <hip/hip_runtime.h>

#define NB 4
#define SEQ 4096
#define DIM 1024
#define DFF 4096
#define KSEL 2048
#define NTOK (NB * SEQ)   // 16384
#define MR (NB * KSEL)    // 8192

typedef float f32x4_t __attribute__((ext_vector_type(4)));
typedef unsigned long u64_t;
typedef unsigned long u64x2_t __attribute__((ext_vector_type(2)));

__device__ __forceinline__ unsigned short f2bf(float f) {
  union { float f; unsigned u; } v; v.f = f;
  unsigned r = v.u + 0x7fffu + ((v.u >> 16) & 1u);  // RNE
  return (unsigned short)(r >> 16);
}

// HW f32->fp8 e4m3 (OCP, RNE, saturating)
__device__ __forceinline__ unsigned char f2fp8(float f) {
  return (unsigned char)(__builtin_amdgcn_cvt_pk_fp8_f32(f, f, 0, false) & 0xff);
}

// fragment-friendly byte permutation within a 128B K-block:
// k = kk*32 + slot*8 + b  ->  pos = slot*32 + kk*8 + b
__device__ __forceinline__ int kperm(int kb) {
  return ((kb >> 3) & 3) * 32 + (kb >> 5) * 8 + (kb & 7);
}

#define GLD16(g, l) __builtin_amdgcn_global_load_lds( \
    (const __attribute__((address_space(1))) void*)(g), \
    (__attribute__((address_space(3))) void*)(l), 16, 0, 0)

// ---- router GEMV (one wave per row) ----
__global__ void router_kernel(const float* __restrict__ x, const float* __restrict__ Wr,
                              const float* __restrict__ br,
                              float* __restrict__ logits, float* __restrict__ scores) {
  int lane = threadIdx.x & 63;
  int wid  = threadIdx.x >> 6;
  int row  = blockIdx.x * 4 + wid;            // 0..16383
  const float4* xr = (const float4*)(x + (size_t)row * DIM);
  const float4* w4 = (const float4*)Wr;
  float sum = 0.f;
#pragma unroll
  for (int i = 0; i < 4; ++i) {
    float4 a = xr[lane + i * 64];
    float4 w = w4[lane + i * 64];
    sum += a.x * w.x + a.y * w.y + a.z * w.z + a.w * w.w;
  }
#pragma unroll
  for (int off = 32; off > 0; off >>= 1) sum += __shfl_down(sum, off);
  if (lane == 0) {
    float l = sum + br[0];
    logits[row] = l;
    scores[row] = 1.f / (1.f + expf(-l));
  }
}

// ---- exact top-k via rank counting (matches jax.lax.top_k tie-break) ----
__global__ void rank_kernel(const float* __restrict__ scores, int* __restrict__ sel) {
  __shared__ float s_sc[SEQ];
  int batch = blockIdx.x >> 8;        // 256 blocks per batch
  int chunk = blockIdx.x & 255;
  int t = threadIdx.x;                // 256
  const float4* sb4 = (const float4*)(scores + batch * SEQ);
  float4* ls4 = (float4*)s_sc;
#pragma unroll
  for (int i = 0; i < 4; ++i) ls4[t + i * 256] = sb4[t + i * 256];
  __syncthreads();
  int tok = chunk * 16 + (t >> 4);    // token this thread contributes to
  int sg  = t & 15;                   // score segment 0..15 (256 scores each)
  float s = s_sc[tok];
  const float4* seg = ls4 + sg * 64;
  int jbase = sg * 256;
  int rank = 0;
#pragma unroll 4
  for (int j4 = 0; j4 < 64; ++j4) {
    float4 v = seg[j4];
    int j = jbase + j4 * 4;
    rank += (v.x > s || (v.x == s && j     < tok)) ? 1 : 0;
    rank += (v.y > s || (v.y == s && j + 1 < tok)) ? 1 : 0;
    rank += (v.z > s || (v.z == s && j + 2 < tok)) ? 1 : 0;
    rank += (v.w > s || (v.w == s && j + 3 < tok)) ? 1 : 0;
  }
#pragma unroll
  for (int off = 8; off > 0; off >>= 1) rank += __shfl_down(rank, off, 16);
  if (sg == 0) sel[batch * SEQ + tok] = (rank < KSEL) ? 1 : 0;
}

// ---- per-batch: softmax over selected scores + prefix-sum compaction ----
__global__ void pack_kernel(const float* __restrict__ scores, const int* __restrict__ sel,
                            int* __restrict__ rows, float* __restrict__ rwv,
                            int* __restrict__ slot) {
  __shared__ float red[16];
  __shared__ int scn[1024];
  int batch = blockIdx.x;
  int t = threadIdx.x;
  const float* sb = scores + batch * SEQ;
  const int* fb = sel + batch * SEQ;
  float sc[4]; int fl[4];
#pragma unroll
  for (int i = 0; i < 4; ++i) { sc[i] = sb[t * 4 + i]; fl[i] = fb[t * 4 + i]; }
  float m = fmaxf(fmaxf(sc[0], sc[1]), fmaxf(sc[2], sc[3]));
#pragma unroll
  for (int off = 32; off > 0; off >>= 1) m = fmaxf(m, __shfl_down(m, off));
  if ((t & 63) == 0) red[t >> 6] = m;
  __syncthreads();
  if (t == 0) { float v = red[0]; for (int i = 1; i < 16; ++i) v = fmaxf(v, red[i]); red[0] = v; }
  __syncthreads();
  m = red[0];
  __syncthreads();
  float ex[4]; float esum = 0.f;
#pragma unroll
  for (int i = 0; i < 4; ++i) { ex[i] = expf(sc[i] - m); if (fl[i]) esum += ex[i]; }
#pragma unroll
  for (int off = 32; off > 0; off >>= 1) esum += __shfl_down(esum, off);
  if ((t & 63) == 0) red[t >> 6] = esum;
  __syncthreads();
  if (t == 0) { float v = 0.f; for (int i = 0; i < 16; ++i) v += red[i]; red[0] = v; }
  __syncthreads();
  float total = red[0];
  int cnt = fl[0] + fl[1] + fl[2] + fl[3];
  scn[t] = cnt;
  __syncthreads();
  for (int off = 1; off < 1024; off <<= 1) {
    int a = scn[t];
    int b = (t >= off) ? scn[t - off] : 0;
    __syncthreads();
    scn[t] = a + b;
    __syncthreads();
  }
  int p = scn[t] - cnt;
#pragma unroll
  for (int i = 0; i < 4; ++i) {
    if (fl[i]) {
      rows[batch * KSEL + p] = t * 4 + i;
      rwv[batch * KSEL + p]  = ex[i] / total;
      slot[batch * SEQ + t * 4 + i] = batch * KSEL + p;
      ++p;
    }
  }
}

// ---- fused: selected rows -> fp8 Xc (kperm layout); unselected -> out ----
__global__ void gather_copy_kernel(const float* __restrict__ x, const int* __restrict__ sel,
                                   const int* __restrict__ slot,
                                   unsigned char* __restrict__ Xc, float* __restrict__ out) {
  int tokg = blockIdx.x;           // 0..16383
  const float4* src = (const float4*)(x + (size_t)tokg * DIM);
  int t = threadIdx.x;             // 256
  float4 v = src[t];
  if (sel[tokg]) {
    unsigned lo = (unsigned)__builtin_amdgcn_cvt_pk_fp8_f32(v.x, v.y, 0, false);
    unsigned both = (unsigned)__builtin_amdgcn_cvt_pk_fp8_f32(v.z, v.w, (int)lo, true);
    int k = t * 4;
    int pos = (k & ~127) + kperm(k & 127);   // pos % 4 == 0 (k%8 in {0,4})
    *(unsigned*)(Xc + (size_t)slot[tokg] * DIM + pos) = both;
  } else {
    ((float4*)(out + (size_t)tokg * DIM))[t] = v;
  }
}

// ---- fused transpose+cast f32 -> fp8 (x16 scale, kperm layout) ----
__global__ void transpose_cast2(const float* __restrict__ W1, unsigned char* __restrict__ W1t,
                                const float* __restrict__ W2, unsigned char* __restrict__ W2t) {
  __shared__ float tl[32][33];
  int bid = blockIdx.x;
  const float* W; unsigned char* Wt; int R, C, bx, by;
  if (bid < 4096) { W = W1; Wt = W1t; R = DIM; C = DFF; bx = bid & 127; by = bid >> 7; }
  else { bid -= 4096; W = W2; Wt = W2t; R = DFF; C = DIM; bx = bid & 31; by = bid >> 5; }
  int c0 = bx * 32;
  int r0 = by * 32;
  int tx = threadIdx.x, ty = threadIdx.y;
#pragma unroll
  for (int i = 0; i < 4; ++i)
    tl[ty + i * 8][tx] = W[(size_t)(r0 + ty + i * 8) * C + c0 + tx];
  __syncthreads();
  int k = r0 + tx;
  int pos = (k & ~127) + kperm(k & 127);
#pragma unroll
  for (int i = 0; i < 4; ++i)
    Wt[(size_t)(c0 + ty + i * 8) * R + pos] = f2fp8(16.f * tl[tx][ty + i * 8]);
}

// ==== 256xBN FP8 MFMA GEMM (R3 structure, BK=128, kperm rows, b128 reads) ====
// 512 threads = 8 waves (2M x 4N), wave tile 128 x BN/4, acc[8][NREP].
// In-row kperm layout makes each lane's 4 kk-fragments 2x16 contiguous bytes
// at slot*32+{0,16} -> ds_read_b128 on 16B units ^((row&7)<<4): the verified
// 0-conflict pattern. Double-buffered LDS; 4 quadrant phases; stage order
// B*,A0,A2,A1,A3; mid-tile vmcnt(S), boundary vmcnt(2) (never 0 till end).
// W pre-scaled x16 -> epilogue multiplies acc by 1/16.
// EPI=1: H = fp8(gelu(acc/16+b1)) in kperm layout;  EPI=2: out = x + rw*(...)
template <int BN, int EPI>
__global__ __launch_bounds__(512, 2)
void gemmf8(const unsigned char* __restrict__ A, const unsigned char* __restrict__ Bt,
            int M, int N, int K,
            const float* __restrict__ bias,
            unsigned char* __restrict__ Hout,
            const float* __restrict__ x,
            const int* __restrict__ rows,
            const float* __restrict__ rwv,
            float* __restrict__ out) {
  constexpr int NREP = BN / 64;            // B frags per wave per kk (4 or 2)
  constexpr int NBC  = BN / 64;            // B stage chunks (64 rows each)
  constexpr int S    = 4 + NBC;            // stage loads per thread per tile
  constexpr int ABY = 256 * 128;           // 32 KB
  constexpr int BBY = BN * 128;
  constexpr int TB = ABY + BBY;
  __shared__ __align__(16) char lds[2 * TB];

  const int t = threadIdx.x;
  const int lane = t & 63;
  const int wid = t >> 6;
  const int wm = wid >> 2;                 // 0..1
  const int wn = wid & 3;                  // 0..3

  // XCD-aware bijective swizzle (gridDim.x % 8 == 0 by construction)
  const int nwg = gridDim.x;
  const int qq = nwg >> 3;
  const int nid = (blockIdx.x & 7) * qq + (blockIdx.x >> 3);
  const int gx = N / BN;
  const int by = nid / gx;
  const int bx = nid - by * gx;
  const int bm0 = by * 256;
  const int bn0 = bx * BN;

  const size_t ldb = (size_t)K;            // row BYTES (fp8: 1 B/elem)
  const char* Ab = (const char*)A;
  const char* Bb = (const char*)Bt;

  // staging: thread t covers LDS bytes [t*16, t*16+16) of each 64-row chunk;
  // chunk row = t>>3, dest slot = t&7, source slot = (t&7)^(row&7)
  const int srow = t >> 3;
  const size_t stage_off = (size_t)srow * ldb + (size_t)((((t & 7) ^ (srow & 7)) * 16));

  // fragment b128 offsets within a 128B kperm row (swizzled 16B units)
  const int arow0 = wm * 128 + (lane & 15);
  const int brow0 = wn * (BN / 4) + (lane & 15);
  const int cbs0 = ((lane >> 4) * 32     ) ^ ((lane & 7) << 4);  // kk0,kk1
  const int cbs1 = ((lane >> 4) * 32 + 16) ^ ((lane & 7) << 4);  // kk2,kk3

  f32x4_t acc[8][NREP];
  f32x4_t zero = {0.f, 0.f, 0.f, 0.f};
#pragma unroll
  for (int i = 0; i < 8; ++i)
#pragma unroll
    for (int j = 0; j < NREP; ++j) acc[i][j] = zero;

  const int NT = K / 128;

  // stage order: B0..B(NBC-1), A0, A2, A1, A3  (last two = strips 4-7, q2/q3)
  auto stage = [&](int b, int kt) {
    char* base = lds + b * TB;
    const char* bbase = Bb + (size_t)bn0 * ldb + (size_t)kt * 128 + stage_off;
#pragma unroll
    for (int c = 0; c < NBC; ++c)
      GLD16(bbase + (size_t)(c * 64) * ldb, base + ABY + t * 16 + c * 8192);
    const char* abase = Ab + (size_t)bm0 * ldb + (size_t)kt * 128 + stage_off;
    const int order[4] = {0, 2, 1, 3};
#pragma unroll
    for (int i = 0; i < 4; ++i) {
      int c = order[i];
      GLD16(abase + (size_t)(c * 64) * ldb, base + t * 16 + c * 8192);
    }
  };

  // prologue: stage tile 0; all but A1,A3 (strips 4-7) must land
  stage(0, 0);
  asm volatile("s_waitcnt vmcnt(2)" ::: "memory");
  __builtin_amdgcn_s_barrier();
  __builtin_amdgcn_sched_barrier(0);

  for (int kt = 0; kt < NT; ++kt) {
    const int b = kt & 1;
    const char* Al = lds + b * TB;
    const char* Bl = Al + ABY;
    const bool sn = (kt + 1 < NT);
    u64_t bq[NREP][4];
    u64_t am[2][4];

    auto rdA = [&](int q) {
#pragma unroll
      for (int mi = 0; mi < 2; ++mi) {
        const char* ap = Al + (arow0 + (2 * q + mi) * 16) * 128;
        u64x2_t lo = *(const u64x2_t*)(ap + cbs0);
        u64x2_t hi = *(const u64x2_t*)(ap + cbs1);
        am[mi][0] = lo[0]; am[mi][1] = lo[1]; am[mi][2] = hi[0]; am[mi][3] = hi[1];
      }
    };
    auto domfma = [&](int q) {
      __builtin_amdgcn_s_setprio(1);
#pragma unroll
      for (int mi = 0; mi < 2; ++mi)
#pragma unroll
        for (int n = 0; n < NREP; ++n)
#pragma unroll
          for (int kk = 0; kk < 4; ++kk)
            acc[2 * q + mi][n] = __builtin_amdgcn_mfma_f32_16x16x32_fp8_fp8(
                (long)am[mi][kk], (long)bq[n][kk], acc[2 * q + mi][n], 0, 0, 0);
      __builtin_amdgcn_s_setprio(0);
    };

    // ---- q0 ----
#pragma unroll
    for (int n = 0; n < NREP; ++n) {
      const char* bp = Bl + (brow0 + n * 16) * 128;
      u64x2_t lo = *(const u64x2_t*)(bp + cbs0);
      u64x2_t hi = *(const u64x2_t*)(bp + cbs1);
      bq[n][0] = lo[0]; bq[n][1] = lo[1]; bq[n][2] = hi[0]; bq[n][3] = hi[1];
    }
    rdA(0);
    if (sn) stage(b ^ 1, kt + 1);
    __builtin_amdgcn_s_barrier();
    domfma(0);
    __builtin_amdgcn_s_barrier();
    // ---- q1 ----
    rdA(1);
    __builtin_amdgcn_s_barrier();
    domfma(1);
    if (sn) {
      if constexpr (S == 8) asm volatile("s_waitcnt vmcnt(8)" ::: "memory");
      else                  asm volatile("s_waitcnt vmcnt(6)" ::: "memory");
    } else {
      asm volatile("s_waitcnt vmcnt(0)" ::: "memory");
    }
    __builtin_amdgcn_s_barrier();
    __builtin_amdgcn_sched_barrier(0);
    // ---- q2 ----
    rdA(2);
    __builtin_amdgcn_s_barrier();
    domfma(2);
    __builtin_amdgcn_s_barrier();
    // ---- q3 ----
    rdA(3);
    __builtin_amdgcn_s_barrier();
    domfma(3);
    if (sn) asm volatile("s_waitcnt vmcnt(2)" ::: "memory");
    __builtin_amdgcn_s_barrier();
    __builtin_amdgcn_sched_barrier(0);
  }

  // epilogue  (C/D: row = (lane>>4)*4 + qi (M), col = lane&15 (N))
  const int rb = (lane >> 4) * 4;
  const int cc = lane & 15;
  float bs[NREP];
#pragma unroll
  for (int n = 0; n < NREP; ++n)
    bs[n] = bias[bn0 + wn * (BN / 4) + n * 16 + cc];
#pragma unroll
  for (int m = 0; m < 8; ++m) {
#pragma unroll
    for (int qi = 0; qi < 4; ++qi) {
      int grow = bm0 + wm * 128 + m * 16 + rb + qi;
      if (EPI == 1) {
#pragma unroll
        for (int n = 0; n < NREP; ++n) {
          int gcol = bn0 + wn * (BN / 4) + n * 16 + cc;
          float v = acc[m][n][qi] * 0.0625f + bs[n];
          float cp = 0.7978845608028654f * (v + 0.044715f * v * v * v);
          float g = v / (1.f + __expf(-2.f * cp));   // tanh-approx gelu
          int pos = (gcol & ~127) + kperm(gcol & 127);
          Hout[(size_t)grow * N + pos] = f2fp8(g);
        }
      } else {
        int batch = grow >> 11;
        int tok = rows[grow];
        float rw = rwv[grow];
        size_t obase = ((size_t)(batch * SEQ + tok)) * DIM;
#pragma unroll
        for (int n = 0; n < NREP; ++n) {
          int gcol = bn0 + wn * (BN / 4) + n * 16 + cc;
          float v = acc[m][n][qi] * 0.0625f + bs[n];
          out[obase + gcol] = x[obase + gcol] + rw * v;
        }
      }
    }
  }
}

// ---- aux BCE loss reduction ----
__global__ void aux_kernel(const float* __restrict__ logits, const int* __restrict__ sel,
                           float* __restrict__ out, int out_size) {
  __shared__ float red[16];
  int t = threadIdx.x;
  float sum = 0.f;
  for (int i = t; i < NTOK; i += 1024) {
    float l = logits[i];
    float tgt = sel[i] ? 1.f : 0.f;
    sum += fmaxf(l, 0.f) - l * tgt + log1pf(expf(-fabsf(l)));
  }
#pragma unroll
  for (int off = 32; off > 0; off >>= 1) sum += __shfl_down(sum, off);
  if ((t & 63) == 0) red[t >> 6] = sum;
  __syncthreads();
  if (t == 0) {
    float v = 0.f;
    for (int i = 0; i < 16; ++i) v += red[i];
    out[out_size - 1] = v / (float)NTOK;
  }
}

extern "C" void kernel_launch(void* const* d_in, const int* in_sizes, int n_in,
                              void* d_out, int out_size, void* d_ws, size_t ws_size,
                              hipStream_t stream) {
  const float* x  = (const float*)d_in[0];
  // d_in[1] = attention_mask (unused by reference)
  const float* Wr = (const float*)d_in[2];
  const float* br = (const float*)d_in[3];
  const float* W1 = (const float*)d_in[4];
  const float* b1 = (const float*)d_in[5];
  const float* W2 = (const float*)d_in[6];
  const float* b2 = (const float*)d_in[7];
  float* out = (float*)d_out;

  char* ws = (char*)d_ws;
  float* logits = (float*)(ws);
  float* scores = (float*)(ws + 65536);
  int*   sel    = (int*)(ws + 131072);
  int*   rows   = (int*)(ws + 196608);
  float* rwv    = (float*)(ws + 229376);
  int*   slot   = (int*)(ws + 262144);
  unsigned char* W1t = (unsigned char*)(ws + 327680);                     // 4 MB
  unsigned char* W2t = (unsigned char*)(ws + 327680 + 4194304);           // 4 MB
  unsigned char* Xc  = (unsigned char*)(ws + 327680 + 2 * 4194304);       // 8 MB
  unsigned char* H   = (unsigned char*)(ws + 327680 + 2 * 4194304 + 8388608);  // 32 MB

  transpose_cast2<<<8192, dim3(32, 8), 0, stream>>>(W1, W1t, W2, W2t);
  router_kernel<<<NTOK / 4, 256, 0, stream>>>(x, Wr, br, logits, scores);
  rank_kernel<<<NTOK / 16, 256, 0, stream>>>(scores, sel);
  pack_kernel<<<NB, 1024, 0, stream>>>(scores, sel, rows, rwv, slot);
  gather_copy_kernel<<<NTOK, 256, 0, stream>>>(x, sel, slot, Xc, out);
  gemmf8<256, 1><<<(MR / 256) * (DFF / 256), 512, 0, stream>>>(
      Xc, W1t, MR, DFF, DIM, b1, H, nullptr, nullptr, nullptr, nullptr);
  gemmf8<128, 2><<<(MR / 256) * (DIM / 128), 512, 0, stream>>>(
      H, W2t, MR, DIM, DFF, b2, nullptr, x, rows, rwv, out);
  aux_kernel<<<1, 1024, 0, stream>>>(logits, sel, out, out_size);
}

// Round 13
// 211.553 us; speedup vs baseline: 1.4942x; 1.0863x over previous
//
#include <hip/hip_runtime.h>

#define NB 4
#define SEQ 4096
#define DIM 1024
#define DFF 4096
#define KSEL 2048
#define NTOK (NB * SEQ)   // 16384
#define MR (NB * KSEL)    // 8192

typedef float f32x4_t __attribute__((ext_vector_type(4)));
typedef unsigned long u64_t;
typedef unsigned long u64x2_t __attribute__((ext_vector_type(2)));

__device__ __forceinline__ unsigned short f2bf(float f) {
  union { float f; unsigned u; } v; v.f = f;
  unsigned r = v.u + 0x7fffu + ((v.u >> 16) & 1u);  // RNE
  return (unsigned short)(r >> 16);
}

// HW f32->fp8 e4m3 (OCP, RNE, saturating)
__device__ __forceinline__ unsigned char f2fp8(float f) {
  return (unsigned char)(__builtin_amdgcn_cvt_pk_fp8_f32(f, f, 0, false) & 0xff);
}

// fragment-friendly byte permutation within a 128B K-block:
// k = kk*32 + slot*8 + b  ->  pos = slot*32 + kk*8 + b
__device__ __forceinline__ int kperm(int kb) {
  return ((kb >> 3) & 3) * 32 + (kb >> 5) * 8 + (kb & 7);
}

#define GLD16(g, l) __builtin_amdgcn_global_load_lds( \
    (const __attribute__((address_space(1))) void*)(g), \
    (__attribute__((address_space(3))) void*)(l), 16, 0, 0)

// ---- router GEMV (one wave per row) ----
__global__ void router_kernel(const float* __restrict__ x, const float* __restrict__ Wr,
                              const float* __restrict__ br,
                              float* __restrict__ logits, float* __restrict__ scores) {
  int lane = threadIdx.x & 63;
  int wid  = threadIdx.x >> 6;
  int row  = blockIdx.x * 4 + wid;            // 0..16383
  const float4* xr = (const float4*)(x + (size_t)row * DIM);
  const float4* w4 = (const float4*)Wr;
  float sum = 0.f;
#pragma unroll
  for (int i = 0; i < 4; ++i) {
    float4 a = xr[lane + i * 64];
    float4 w = w4[lane + i * 64];
    sum += a.x * w.x + a.y * w.y + a.z * w.z + a.w * w.w;
  }
#pragma unroll
  for (int off = 32; off > 0; off >>= 1) sum += __shfl_down(sum, off);
  if (lane == 0) {
    float l = sum + br[0];
    logits[row] = l;
    scores[row] = 1.f / (1.f + expf(-l));
  }
}

// ---- exact top-k via rank counting (matches jax.lax.top_k tie-break) ----
__global__ void rank_kernel(const float* __restrict__ scores, int* __restrict__ sel) {
  __shared__ float s_sc[SEQ];
  int batch = blockIdx.x >> 8;        // 256 blocks per batch
  int chunk = blockIdx.x & 255;
  int t = threadIdx.x;                // 256
  const float4* sb4 = (const float4*)(scores + batch * SEQ);
  float4* ls4 = (float4*)s_sc;
#pragma unroll
  for (int i = 0; i < 4; ++i) ls4[t + i * 256] = sb4[t + i * 256];
  __syncthreads();
  int tok = chunk * 16 + (t >> 4);    // token this thread contributes to
  int sg  = t & 15;                   // score segment 0..15 (256 scores each)
  float s = s_sc[tok];
  const float4* seg = ls4 + sg * 64;
  int jbase = sg * 256;
  int rank = 0;
#pragma unroll 4
  for (int j4 = 0; j4 < 64; ++j4) {
    float4 v = seg[j4];
    int j = jbase + j4 * 4;
    rank += (v.x > s || (v.x == s && j     < tok)) ? 1 : 0;
    rank += (v.y > s || (v.y == s && j + 1 < tok)) ? 1 : 0;
    rank += (v.z > s || (v.z == s && j + 2 < tok)) ? 1 : 0;
    rank += (v.w > s || (v.w == s && j + 3 < tok)) ? 1 : 0;
  }
#pragma unroll
  for (int off = 8; off > 0; off >>= 1) rank += __shfl_down(rank, off, 16);
  if (sg == 0) sel[batch * SEQ + tok] = (rank < KSEL) ? 1 : 0;
}

// ---- per-batch: softmax over selected scores + prefix-sum compaction ----
__global__ void pack_kernel(const float* __restrict__ scores, const int* __restrict__ sel,
                            int* __restrict__ rows, float* __restrict__ rwv,
                            int* __restrict__ slot) {
  __shared__ float red[16];
  __shared__ int scn[1024];
  int batch = blockIdx.x;
  int t = threadIdx.x;
  const float* sb = scores + batch * SEQ;
  const int* fb = sel + batch * SEQ;
  float sc[4]; int fl[4];
#pragma unroll
  for (int i = 0; i < 4; ++i) { sc[i] = sb[t * 4 + i]; fl[i] = fb[t * 4 + i]; }
  float m = fmaxf(fmaxf(sc[0], sc[1]), fmaxf(sc[2], sc[3]));
#pragma unroll
  for (int off = 32; off > 0; off >>= 1) m = fmaxf(m, __shfl_down(m, off));
  if ((t & 63) == 0) red[t >> 6] = m;
  __syncthreads();
  if (t == 0) { float v = red[0]; for (int i = 1; i < 16; ++i) v = fmaxf(v, red[i]); red[0] = v; }
  __syncthreads();
  m = red[0];
  __syncthreads();
  float ex[4]; float esum = 0.f;
#pragma unroll
  for (int i = 0; i < 4; ++i) { ex[i] = expf(sc[i] - m); if (fl[i]) esum += ex[i]; }
#pragma unroll
  for (int off = 32; off > 0; off >>= 1) esum += __shfl_down(esum, off);
  if ((t & 63) == 0) red[t >> 6] = esum;
  __syncthreads();
  if (t == 0) { float v = 0.f; for (int i = 0; i < 16; ++i) v += red[i]; red[0] = v; }
  __syncthreads();
  float total = red[0];
  int cnt = fl[0] + fl[1] + fl[2] + fl[3];
  scn[t] = cnt;
  __syncthreads();
  for (int off = 1; off < 1024; off <<= 1) {
    int a = scn[t];
    int b = (t >= off) ? scn[t - off] : 0;
    __syncthreads();
    scn[t] = a + b;
    __syncthreads();
  }
  int p = scn[t] - cnt;
#pragma unroll
  for (int i = 0; i < 4; ++i) {
    if (fl[i]) {
      rows[batch * KSEL + p] = t * 4 + i;
      rwv[batch * KSEL + p]  = ex[i] / total;
      slot[batch * SEQ + t * 4 + i] = batch * KSEL + p;
      ++p;
    }
  }
}

// ---- fused: selected rows -> fp8 Xc (kperm layout); unselected -> out ----
__global__ void gather_copy_kernel(const float* __restrict__ x, const int* __restrict__ sel,
                                   const int* __restrict__ slot,
                                   unsigned char* __restrict__ Xc, float* __restrict__ out) {
  int tokg = blockIdx.x;           // 0..16383
  const float4* src = (const float4*)(x + (size_t)tokg * DIM);
  int t = threadIdx.x;             // 256
  float4 v = src[t];
  if (sel[tokg]) {
    unsigned lo = (unsigned)__builtin_amdgcn_cvt_pk_fp8_f32(v.x, v.y, 0, false);
    unsigned both = (unsigned)__builtin_amdgcn_cvt_pk_fp8_f32(v.z, v.w, (int)lo, true);
    int k = t * 4;
    int pos = (k & ~127) + kperm(k & 127);   // pos % 4 == 0 (k%8 in {0,4})
    *(unsigned*)(Xc + (size_t)slot[tokg] * DIM + pos) = both;
  } else {
    ((float4*)(out + (size_t)tokg * DIM))[t] = v;
  }
}

// ---- fused transpose+cast f32 -> fp8 (x16 scale, kperm layout) ----
__global__ void transpose_cast2(const float* __restrict__ W1, unsigned char* __restrict__ W1t,
                                const float* __restrict__ W2, unsigned char* __restrict__ W2t) {
  __shared__ float tl[32][33];
  int bid = blockIdx.x;
  const float* W; unsigned char* Wt; int R, C, bx, by;
  if (bid < 4096) { W = W1; Wt = W1t; R = DIM; C = DFF; bx = bid & 127; by = bid >> 7; }
  else { bid -= 4096; W = W2; Wt = W2t; R = DFF; C = DIM; bx = bid & 31; by = bid >> 5; }
  int c0 = bx * 32;
  int r0 = by * 32;
  int tx = threadIdx.x, ty = threadIdx.y;
#pragma unroll
  for (int i = 0; i < 4; ++i)
    tl[ty + i * 8][tx] = W[(size_t)(r0 + ty + i * 8) * C + c0 + tx];
  __syncthreads();
  int k = r0 + tx;
  int pos = (k & ~127) + kperm(k & 127);
#pragma unroll
  for (int i = 0; i < 4; ++i)
    Wt[(size_t)(c0 + ty + i * 8) * R + pos] = f2fp8(16.f * tl[tx][ty + i * 8]);
}

// ==== m145-structure FP8 GEMM: 128x128 tile, BK=128, single 32KB buffer ====
// 256 threads = 4 waves (2M x 2N), wave tile 64x64, acc[4][4].
// Loop: stage (8 GLD16/thread) -> __syncthreads -> 16 b128 frag reads +
// 64 MFMA -> __syncthreads. ~3 blocks/CU resident: the per-tile drain is
// hidden by co-resident blocks (m114/m145: fp8 995 TF with this shape).
// kperm in-row layout + XOR swizzle byte^=((row&7)<<4) via pre-swizzled
// global source -> ds_read_b128 on 16B units (verified pattern).
// W pre-scaled x16 -> epilogue multiplies acc by 1/16.
// EPI=1: H = fp8(gelu(acc/16+b1)) kperm layout;  EPI=2: out = x + rw*(...)
template <int EPI>
__global__ __launch_bounds__(256)
void gemm11(const unsigned char* __restrict__ A, const unsigned char* __restrict__ Bt,
            int M, int N, int K,
            const float* __restrict__ bias,
            unsigned char* __restrict__ Hout,
            const float* __restrict__ x,
            const int* __restrict__ rows,
            const float* __restrict__ rwv,
            float* __restrict__ out) {
  __shared__ __align__(16) unsigned char As[128 * 128];   // 16 KB
  __shared__ __align__(16) unsigned char Bs[128 * 128];   // 16 KB

  const int t = threadIdx.x;
  const int lane = t & 63;
  const int wid = t >> 6;
  const int wm = wid >> 1;                 // 0..1
  const int wn = wid & 1;                  // 0..1

  // XCD-aware bijective swizzle (gridDim.x % 8 == 0 by construction)
  const int nwg = gridDim.x;
  const int qq = nwg >> 3;
  const int nid = (blockIdx.x & 7) * qq + (blockIdx.x >> 3);
  const int gx = N / 128;
  const int by = nid / gx;
  const int bx = nid - by * gx;
  const int bm0 = by * 128;
  const int bn0 = bx * 128;

  const size_t ldb = (size_t)K;            // row BYTES (fp8)
  const char* Ab = (const char*)A + (size_t)bm0 * ldb;
  const char* Bb = (const char*)Bt + (size_t)bn0 * ldb;
  char* AsB = (char*)As;
  char* BsB = (char*)Bs;

  // staging: thread t covers 16B of each 32-row chunk; row = t>>3 (0..31),
  // dest slot = t&7, source slot = (t&7)^(row&7)
  const int srow = t >> 3;
  const size_t stage_off = (size_t)srow * ldb + (size_t)((((t & 7) ^ (srow & 7)) * 16));

  // fragment b128 offsets within a 128B kperm row (swizzled 16B units)
  const int cbs0 = ((lane >> 4) * 32     ) ^ ((lane & 7) << 4);  // kk0,kk1
  const int cbs1 = ((lane >> 4) * 32 + 16) ^ ((lane & 7) << 4);  // kk2,kk3

  f32x4_t acc[4][4];
  f32x4_t zero = {0.f, 0.f, 0.f, 0.f};
#pragma unroll
  for (int i = 0; i < 4; ++i)
#pragma unroll
    for (int j = 0; j < 4; ++j) acc[i][j] = zero;

  const int NT = K / 128;

  for (int kt = 0; kt < NT; ++kt) {
    const size_t kb = (size_t)kt * 128 + stage_off;
#pragma unroll
    for (int c = 0; c < 4; ++c)
      GLD16(Ab + kb + (size_t)(c * 32) * ldb, AsB + t * 16 + c * 4096);
#pragma unroll
    for (int c = 0; c < 4; ++c)
      GLD16(Bb + kb + (size_t)(c * 32) * ldb, BsB + t * 16 + c * 4096);
    __syncthreads();

    u64_t am[4][4], bq[4][4];
#pragma unroll
    for (int i = 0; i < 4; ++i) {
      const char* ap = AsB + (wm * 64 + i * 16 + (lane & 15)) * 128;
      u64x2_t lo = *(const u64x2_t*)(ap + cbs0);
      u64x2_t hi = *(const u64x2_t*)(ap + cbs1);
      am[i][0] = lo[0]; am[i][1] = lo[1]; am[i][2] = hi[0]; am[i][3] = hi[1];
    }
#pragma unroll
    for (int j = 0; j < 4; ++j) {
      const char* bp = BsB + (wn * 64 + j * 16 + (lane & 15)) * 128;
      u64x2_t lo = *(const u64x2_t*)(bp + cbs0);
      u64x2_t hi = *(const u64x2_t*)(bp + cbs1);
      bq[j][0] = lo[0]; bq[j][1] = lo[1]; bq[j][2] = hi[0]; bq[j][3] = hi[1];
    }
    __builtin_amdgcn_s_setprio(1);
#pragma unroll
    for (int i = 0; i < 4; ++i)
#pragma unroll
      for (int j = 0; j < 4; ++j)
#pragma unroll
        for (int kk = 0; kk < 4; ++kk)
          acc[i][j] = __builtin_amdgcn_mfma_f32_16x16x32_fp8_fp8(
              (long)am[i][kk], (long)bq[j][kk], acc[i][j], 0, 0, 0);
    __builtin_amdgcn_s_setprio(0);
    __syncthreads();
  }

  // epilogue  (C/D: row = (lane>>4)*4 + qi (M), col = lane&15 (N))
  const int rb = (lane >> 4) * 4;
  const int cc = lane & 15;
#pragma unroll
  for (int i = 0; i < 4; ++i) {
#pragma unroll
    for (int qi = 0; qi < 4; ++qi) {
      int grow = bm0 + wm * 64 + i * 16 + rb + qi;
      if (EPI == 1) {
#pragma unroll
        for (int j = 0; j < 4; ++j) {
          int gcol = bn0 + wn * 64 + j * 16 + cc;
          float v = acc[i][j][qi] * 0.0625f + bias[gcol];
          float cp = 0.7978845608028654f * (v + 0.044715f * v * v * v);
          float g = v / (1.f + __expf(-2.f * cp));   // tanh-approx gelu
          int pos = (gcol & ~127) + kperm(gcol & 127);
          Hout[(size_t)grow * N + pos] = f2fp8(g);
        }
      } else {
        int batch = grow >> 11;
        int tok = rows[grow];
        float rw = rwv[grow];
        size_t obase = ((size_t)(batch * SEQ + tok)) * DIM;
#pragma unroll
        for (int j = 0; j < 4; ++j) {
          int gcol = bn0 + wn * 64 + j * 16 + cc;
          float v = acc[i][j][qi] * 0.0625f + bias[gcol];
          out[obase + gcol] = x[obase + gcol] + rw * v;
        }
      }
    }
  }
}

// ---- aux BCE loss reduction ----
__global__ void aux_kernel(const float* __restrict__ logits, const int* __restrict__ sel,
                           float* __restrict__ out, int out_size) {
  __shared__ float red[16];
  int t = threadIdx.x;
  float sum = 0.f;
  for (int i = t; i < NTOK; i += 1024) {
    float l = logits[i];
    float tgt = sel[i] ? 1.f : 0.f;
    sum += fmaxf(l, 0.f) - l * tgt + log1pf(expf(-fabsf(l)));
  }
#pragma unroll
  for (int off = 32; off > 0; off >>= 1) sum += __shfl_down(sum, off);
  if ((t & 63) == 0) red[t >> 6] = sum;
  __syncthreads();
  if (t == 0) {
    float v = 0.f;
    for (int i = 0; i < 16; ++i) v += red[i];
    out[out_size - 1] = v / (float)NTOK;
  }
}

extern "C" void kernel_launch(void* const* d_in, const int* in_sizes, int n_in,
                              void* d_out, int out_size, void* d_ws, size_t ws_size,
                              hipStream_t stream) {
  const float* x  = (const float*)d_in[0];
  // d_in[1] = attention_mask (unused by reference)
  const float* Wr = (const float*)d_in[2];
  const float* br = (const float*)d_in[3];
  const float* W1 = (const float*)d_in[4];
  const float* b1 = (const float*)d_in[5];
  const float* W2 = (const float*)d_in[6];
  const float* b2 = (const float*)d_in[7];
  float* out = (float*)d_out;

  char* ws = (char*)d_ws;
  float* logits = (float*)(ws);
  float* scores = (float*)(ws + 65536);
  int*   sel    = (int*)(ws + 131072);
  int*   rows   = (int*)(ws + 196608);
  float* rwv    = (float*)(ws + 229376);
  int*   slot   = (int*)(ws + 262144);
  unsigned char* W1t = (unsigned char*)(ws + 327680);                     // 4 MB
  unsigned char* W2t = (unsigned char*)(ws + 327680 + 4194304);           // 4 MB
  unsigned char* Xc  = (unsigned char*)(ws + 327680 + 2 * 4194304);       // 8 MB
  unsigned char* H   = (unsigned char*)(ws + 327680 + 2 * 4194304 + 8388608);  // 32 MB

  transpose_cast2<<<8192, dim3(32, 8), 0, stream>>>(W1, W1t, W2, W2t);
  router_kernel<<<NTOK / 4, 256, 0, stream>>>(x, Wr, br, logits, scores);
  rank_kernel<<<NTOK / 16, 256, 0, stream>>>(scores, sel);
  pack_kernel<<<NB, 1024, 0, stream>>>(scores, sel, rows, rwv, slot);
  gather_copy_kernel<<<NTOK, 256, 0, stream>>>(x, sel, slot, Xc, out);
  gemm11<1><<<(MR / 128) * (DFF / 128), 256, 0, stream>>>(
      Xc, W1t, MR, DFF, DIM, b1, H, nullptr, nullptr, nullptr, nullptr);
  gemm11<2><<<(MR / 128) * (DIM / 128), 256, 0, stream>>>(
      H, W2t, MR, DIM, DFF, b2, nullptr, x, rows, rwv, out);
  aux_kernel<<<1, 1024, 0, stream>>>(logits, sel, out, out_size);
}

// Round 14
// 203.739 us; speedup vs baseline: 1.5515x; 1.0384x over previous
//
#include <hip/hip_runtime.h>

#define NB 4
#define SEQ 4096
#define DIM 1024
#define DFF 4096
#define KSEL 2048
#define NTOK (NB * SEQ)   // 16384
#define MR (NB * KSEL)    // 8192

typedef float f32x4_t __attribute__((ext_vector_type(4)));
typedef unsigned long u64_t;
typedef unsigned long u64x2_t __attribute__((ext_vector_type(2)));
typedef int i32x8_t __attribute__((ext_vector_type(8)));

// HW f32->fp8 e4m3 (OCP, RNE, saturating)
__device__ __forceinline__ unsigned char f2fp8(float f) {
  return (unsigned char)(__builtin_amdgcn_cvt_pk_fp8_f32(f, f, 0, false) & 0xff);
}

// fragment-friendly byte permutation within a 128B K-block:
// k = kk*32 + slot*8 + b  ->  pos = slot*32 + kk*8 + b
__device__ __forceinline__ int kperm(int kb) {
  return ((kb >> 3) & 3) * 32 + (kb >> 5) * 8 + (kb & 7);
}

#define GLD16(g, l) __builtin_amdgcn_global_load_lds( \
    (const __attribute__((address_space(1))) void*)(g), \
    (__attribute__((address_space(3))) void*)(l), 16, 0, 0)

// ---- fused prep: W1/W2 transpose+cast (blocks 0..8191) + router GEMV
//      (blocks 8192..12287) -- independent work, one launch ----
__global__ void prep_kernel(const float* __restrict__ W1, unsigned char* __restrict__ W1t,
                            const float* __restrict__ W2, unsigned char* __restrict__ W2t,
                            const float* __restrict__ x, const float* __restrict__ Wr,
                            const float* __restrict__ br,
                            float* __restrict__ logits, float* __restrict__ scores) {
  __shared__ float tl[32][33];
  int bid = blockIdx.x;
  if (bid < 8192) {
    const float* W; unsigned char* Wt; int R, C, bx, by;
    if (bid < 4096) { W = W1; Wt = W1t; R = DIM; C = DFF; bx = bid & 127; by = bid >> 7; }
    else { bid -= 4096; W = W2; Wt = W2t; R = DFF; C = DIM; bx = bid & 31; by = bid >> 5; }
    int c0 = bx * 32;
    int r0 = by * 32;
    int tx = threadIdx.x & 31, ty = threadIdx.x >> 5;
#pragma unroll
    for (int i = 0; i < 4; ++i)
      tl[ty + i * 8][tx] = W[(size_t)(r0 + ty + i * 8) * C + c0 + tx];
    __syncthreads();
    int k = r0 + tx;
    int pos = (k & ~127) + kperm(k & 127);
#pragma unroll
    for (int i = 0; i < 4; ++i)
      Wt[(size_t)(c0 + ty + i * 8) * R + pos] = f2fp8(16.f * tl[tx][ty + i * 8]);
  } else {
    int lane = threadIdx.x & 63;
    int wid  = threadIdx.x >> 6;
    int row  = (bid - 8192) * 4 + wid;        // 0..16383
    const float4* xr = (const float4*)(x + (size_t)row * DIM);
    const float4* w4 = (const float4*)Wr;
    float sum = 0.f;
#pragma unroll
    for (int i = 0; i < 4; ++i) {
      float4 a = xr[lane + i * 64];
      float4 w = w4[lane + i * 64];
      sum += a.x * w.x + a.y * w.y + a.z * w.z + a.w * w.w;
    }
#pragma unroll
    for (int off = 32; off > 0; off >>= 1) sum += __shfl_down(sum, off);
    if (lane == 0) {
      float l = sum + br[0];
      logits[row] = l;
      scores[row] = 1.f / (1.f + expf(-l));
    }
  }
}

// ---- exact top-k via rank counting (matches jax.lax.top_k tie-break) ----
__global__ void rank_kernel(const float* __restrict__ scores, int* __restrict__ sel) {
  __shared__ float s_sc[SEQ];
  int batch = blockIdx.x >> 8;        // 256 blocks per batch
  int chunk = blockIdx.x & 255;
  int t = threadIdx.x;                // 256
  const float4* sb4 = (const float4*)(scores + batch * SEQ);
  float4* ls4 = (float4*)s_sc;
#pragma unroll
  for (int i = 0; i < 4; ++i) ls4[t + i * 256] = sb4[t + i * 256];
  __syncthreads();
  int tok = chunk * 16 + (t >> 4);    // token this thread contributes to
  int sg  = t & 15;                   // score segment 0..15 (256 scores each)
  float s = s_sc[tok];
  const float4* seg = ls4 + sg * 64;
  int jbase = sg * 256;
  int rank = 0;
#pragma unroll 4
  for (int j4 = 0; j4 < 64; ++j4) {
    float4 v = seg[j4];
    int j = jbase + j4 * 4;
    rank += (v.x > s || (v.x == s && j     < tok)) ? 1 : 0;
    rank += (v.y > s || (v.y == s && j + 1 < tok)) ? 1 : 0;
    rank += (v.z > s || (v.z == s && j + 2 < tok)) ? 1 : 0;
    rank += (v.w > s || (v.w == s && j + 3 < tok)) ? 1 : 0;
  }
#pragma unroll
  for (int off = 8; off > 0; off >>= 1) rank += __shfl_down(rank, off, 16);
  if (sg == 0) sel[batch * SEQ + tok] = (rank < KSEL) ? 1 : 0;
}

// ---- per-batch: softmax over selected scores + prefix-sum compaction ----
__global__ void pack_kernel(const float* __restrict__ scores, const int* __restrict__ sel,
                            int* __restrict__ rows, float* __restrict__ rwv,
                            int* __restrict__ slot) {
  __shared__ float red[16];
  __shared__ int scn[1024];
  int batch = blockIdx.x;
  int t = threadIdx.x;
  const float* sb = scores + batch * SEQ;
  const int* fb = sel + batch * SEQ;
  float sc[4]; int fl[4];
#pragma unroll
  for (int i = 0; i < 4; ++i) { sc[i] = sb[t * 4 + i]; fl[i] = fb[t * 4 + i]; }
  float m = fmaxf(fmaxf(sc[0], sc[1]), fmaxf(sc[2], sc[3]));
#pragma unroll
  for (int off = 32; off > 0; off >>= 1) m = fmaxf(m, __shfl_down(m, off));
  if ((t & 63) == 0) red[t >> 6] = m;
  __syncthreads();
  if (t == 0) { float v = red[0]; for (int i = 1; i < 16; ++i) v = fmaxf(v, red[i]); red[0] = v; }
  __syncthreads();
  m = red[0];
  __syncthreads();
  float ex[4]; float esum = 0.f;
#pragma unroll
  for (int i = 0; i < 4; ++i) { ex[i] = expf(sc[i] - m); if (fl[i]) esum += ex[i]; }
#pragma unroll
  for (int off = 32; off > 0; off >>= 1) esum += __shfl_down(esum, off);
  if ((t & 63) == 0) red[t >> 6] = esum;
  __syncthreads();
  if (t == 0) { float v = 0.f; for (int i = 0; i < 16; ++i) v += red[i]; red[0] = v; }
  __syncthreads();
  float total = red[0];
  int cnt = fl[0] + fl[1] + fl[2] + fl[3];
  scn[t] = cnt;
  __syncthreads();
  for (int off = 1; off < 1024; off <<= 1) {
    int a = scn[t];
    int b = (t >= off) ? scn[t - off] : 0;
    __syncthreads();
    scn[t] = a + b;
    __syncthreads();
  }
  int p = scn[t] - cnt;
#pragma unroll
  for (int i = 0; i < 4; ++i) {
    if (fl[i]) {
      rows[batch * KSEL + p] = t * 4 + i;
      rwv[batch * KSEL + p]  = ex[i] / total;
      slot[batch * SEQ + t * 4 + i] = batch * KSEL + p;
      ++p;
    }
  }
}

// ---- fused: selected rows -> fp8 Xc (kperm layout); unselected -> out ----
__global__ void gather_copy_kernel(const float* __restrict__ x, const int* __restrict__ sel,
                                   const int* __restrict__ slot,
                                   unsigned char* __restrict__ Xc, float* __restrict__ out) {
  int tokg = blockIdx.x;           // 0..16383
  const float4* src = (const float4*)(x + (size_t)tokg * DIM);
  int t = threadIdx.x;             // 256
  float4 v = src[t];
  if (sel[tokg]) {
    unsigned lo = (unsigned)__builtin_amdgcn_cvt_pk_fp8_f32(v.x, v.y, 0, false);
    unsigned both = (unsigned)__builtin_amdgcn_cvt_pk_fp8_f32(v.z, v.w, (int)lo, true);
    int k = t * 4;
    int pos = (k & ~127) + kperm(k & 127);   // pos % 4 == 0 (k%8 in {0,4})
    *(unsigned*)(Xc + (size_t)slot[tokg] * DIM + pos) = both;
  } else {
    ((float4*)(out + (size_t)tokg * DIM))[t] = v;
  }
}

// ==== m145-structure MX-FP8 GEMM: 128x128 tile, BK=128, 32KB buffer ====
// 256 threads = 4 waves (2M x 2N), wave tile 64x64, acc[4][4].
// Loop: stage (8 GLD16/thread) -> __syncthreads -> 16 b128 frag reads +
// 16 mfma_scale_f32_16x16x128_f8f6f4 (scales=1.0 => exact fp8 product;
// 2x the non-scaled fp8 rate, ladder m148) -> __syncthreads.
// Layout-robust: A and B use the SAME kperm+swizzle register packing, so the
// positional K-pairing inside the instruction is consistent for any k<->pos
// bijection; uniform scales make 32-block boundaries irrelevant.
// kperm in-row layout + XOR swizzle byte^=((row&7)<<4) via pre-swizzled
// global source -> ds_read_b128 on 16B units (2-way max, free).
// W pre-scaled x16 -> epilogue multiplies acc by 1/16.
// EPI=1: H = fp8(gelu(acc/16+b1)) kperm layout;  EPI=2: out = x + rw*(...)
template <int EPI>
__global__ __launch_bounds__(256)
void gemm12(const unsigned char* __restrict__ A, const unsigned char* __restrict__ Bt,
            int M, int N, int K,
            const float* __restrict__ bias,
            unsigned char* __restrict__ Hout,
            const float* __restrict__ x,
            const int* __restrict__ rows,
            const float* __restrict__ rwv,
            float* __restrict__ out) {
  __shared__ __align__(16) unsigned char As[128 * 128];   // 16 KB
  __shared__ __align__(16) unsigned char Bs[128 * 128];   // 16 KB

  const int t = threadIdx.x;
  const int lane = t & 63;
  const int wid = t >> 6;
  const int wm = wid >> 1;                 // 0..1
  const int wn = wid & 1;                  // 0..1

  // XCD-aware bijective swizzle (gridDim.x % 8 == 0 by construction)
  const int nwg = gridDim.x;
  const int qq = nwg >> 3;
  const int nid = (blockIdx.x & 7) * qq + (blockIdx.x >> 3);
  const int gx = N / 128;
  const int by = nid / gx;
  const int bx = nid - by * gx;
  const int bm0 = by * 128;
  const int bn0 = bx * 128;

  const size_t ldb = (size_t)K;            // row BYTES (fp8)
  const char* Ab = (const char*)A + (size_t)bm0 * ldb;
  const char* Bb = (const char*)Bt + (size_t)bn0 * ldb;
  char* AsB = (char*)As;
  char* BsB = (char*)Bs;

  // staging: thread t covers 16B of each 32-row chunk; row = t>>3 (0..31),
  // dest slot = t&7, source slot = (t&7)^(row&7)
  const int srow = t >> 3;
  const size_t stage_off = (size_t)srow * ldb + (size_t)((((t & 7) ^ (srow & 7)) * 16));

  // fragment b128 offsets within a 128B kperm row (swizzled 16B units)
  const int cbs0 = ((lane >> 4) * 32     ) ^ ((lane & 7) << 4);  // kk0,kk1
  const int cbs1 = ((lane >> 4) * 32 + 16) ^ ((lane & 7) << 4);  // kk2,kk3

  f32x4_t acc[4][4];
  f32x4_t zero = {0.f, 0.f, 0.f, 0.f};
#pragma unroll
  for (int i = 0; i < 4; ++i)
#pragma unroll
    for (int j = 0; j < 4; ++j) acc[i][j] = zero;

  const int NT = K / 128;

  for (int kt = 0; kt < NT; ++kt) {
    const size_t kb = (size_t)kt * 128 + stage_off;
#pragma unroll
    for (int c = 0; c < 4; ++c)
      GLD16(Ab + kb + (size_t)(c * 32) * ldb, AsB + t * 16 + c * 4096);
#pragma unroll
    for (int c = 0; c < 4; ++c)
      GLD16(Bb + kb + (size_t)(c * 32) * ldb, BsB + t * 16 + c * 4096);
    __syncthreads();

    i32x8_t am[4], bq[4];
#pragma unroll
    for (int i = 0; i < 4; ++i) {
      const char* ap = AsB + (wm * 64 + i * 16 + (lane & 15)) * 128;
      union { u64x2_t q[2]; i32x8_t v; } u;
      u.q[0] = *(const u64x2_t*)(ap + cbs0);
      u.q[1] = *(const u64x2_t*)(ap + cbs1);
      am[i] = u.v;
    }
#pragma unroll
    for (int j = 0; j < 4; ++j) {
      const char* bp = BsB + (wn * 64 + j * 16 + (lane & 15)) * 128;
      union { u64x2_t q[2]; i32x8_t v; } u;
      u.q[0] = *(const u64x2_t*)(bp + cbs0);
      u.q[1] = *(const u64x2_t*)(bp + cbs1);
      bq[j] = u.v;
    }
    __builtin_amdgcn_s_setprio(1);
#pragma unroll
    for (int i = 0; i < 4; ++i)
#pragma unroll
      for (int j = 0; j < 4; ++j)
        acc[i][j] = __builtin_amdgcn_mfma_scale_f32_16x16x128_f8f6f4(
            am[i], bq[j], acc[i][j], 0, 0,
            0, 0x7f7f7f7f, 0, 0x7f7f7f7f);   // E8M0 0x7f = 1.0 scales
    __builtin_amdgcn_s_setprio(0);
    __syncthreads();
  }

  // epilogue  (C/D: row = (lane>>4)*4 + qi (M), col = lane&15 (N))
  const int rb = (lane >> 4) * 4;
  const int cc = lane & 15;
#pragma unroll
  for (int i = 0; i < 4; ++i) {
#pragma unroll
    for (int qi = 0; qi < 4; ++qi) {
      int grow = bm0 + wm * 64 + i * 16 + rb + qi;
      if (EPI == 1) {
#pragma unroll
        for (int j = 0; j < 4; ++j) {
          int gcol = bn0 + wn * 64 + j * 16 + cc;
          float v = acc[i][j][qi] * 0.0625f + bias[gcol];
          float cp = 0.7978845608028654f * (v + 0.044715f * v * v * v);
          float g = v / (1.f + __expf(-2.f * cp));   // tanh-approx gelu
          int pos = (gcol & ~127) + kperm(gcol & 127);
          Hout[(size_t)grow * N + pos] = f2fp8(g);
        }
      } else {
        int batch = grow >> 11;
        int tok = rows[grow];
        float rw = rwv[grow];
        size_t obase = ((size_t)(batch * SEQ + tok)) * DIM;
#pragma unroll
        for (int j = 0; j < 4; ++j) {
          int gcol = bn0 + wn * 64 + j * 16 + cc;
          float v = acc[i][j][qi] * 0.0625f + bias[gcol];
          out[obase + gcol] = x[obase + gcol] + rw * v;
        }
      }
    }
  }
}

// ---- aux BCE loss reduction ----
__global__ void aux_kernel(const float* __restrict__ logits, const int* __restrict__ sel,
                           float* __restrict__ out, int out_size) {
  __shared__ float red[16];
  int t = threadIdx.x;
  float sum = 0.f;
  for (int i = t; i < NTOK; i += 1024) {
    float l = logits[i];
    float tgt = sel[i] ? 1.f : 0.f;
    sum += fmaxf(l, 0.f) - l * tgt + log1pf(expf(-fabsf(l)));
  }
#pragma unroll
  for (int off = 32; off > 0; off >>= 1) sum += __shfl_down(sum, off);
  if ((t & 63) == 0) red[t >> 6] = sum;
  __syncthreads();
  if (t == 0) {
    float v = 0.f;
    for (int i = 0; i < 16; ++i) v += red[i];
    out[out_size - 1] = v / (float)NTOK;
  }
}

extern "C" void kernel_launch(void* const* d_in, const int* in_sizes, int n_in,
                              void* d_out, int out_size, void* d_ws, size_t ws_size,
                              hipStream_t stream) {
  const float* x  = (const float*)d_in[0];
  // d_in[1] = attention_mask (unused by reference)
  const float* Wr = (const float*)d_in[2];
  const float* br = (const float*)d_in[3];
  const float* W1 = (const float*)d_in[4];
  const float* b1 = (const float*)d_in[5];
  const float* W2 = (const float*)d_in[6];
  const float* b2 = (const float*)d_in[7];
  float* out = (float*)d_out;

  char* ws = (char*)d_ws;
  float* logits = (float*)(ws);
  float* scores = (float*)(ws + 65536);
  int*   sel    = (int*)(ws + 131072);
  int*   rows   = (int*)(ws + 196608);
  float* rwv    = (float*)(ws + 229376);
  int*   slot   = (int*)(ws + 262144);
  unsigned char* W1t = (unsigned char*)(ws + 327680);                     // 4 MB
  unsigned char* W2t = (unsigned char*)(ws + 327680 + 4194304);           // 4 MB
  unsigned char* Xc  = (unsigned char*)(ws + 327680 + 2 * 4194304);       // 8 MB
  unsigned char* H   = (unsigned char*)(ws + 327680 + 2 * 4194304 + 8388608);  // 32 MB

  prep_kernel<<<12288, 256, 0, stream>>>(W1, W1t, W2, W2t, x, Wr, br, logits, scores);
  rank_kernel<<<NTOK / 16, 256, 0, stream>>>(scores, sel);
  pack_kernel<<<NB, 1024, 0, stream>>>(scores, sel, rows, rwv, slot);
  gather_copy_kernel<<<NTOK, 256, 0, stream>>>(x, sel, slot, Xc, out);
  gemm12<1><<<(MR / 128) * (DFF / 128), 256, 0, stream>>>(
      Xc, W1t, MR, DFF, DIM, b1, H, nullptr, nullptr, nullptr, nullptr);
  gemm12<2><<<(MR / 128) * (DIM / 128), 256, 0, stream>>>(
      H, W2t, MR, DIM, DFF, b2, nullptr, x, rows, rwv, out);
  aux_kernel<<<1, 1024, 0, stream>>>(logits, sel, out, out_size);
}